// Round 19
// baseline (170.499 us; speedup 1.0000x reference)
//
#include <hip/hip_runtime.h>
#include <math.h>

#define S_LEN  1024
#define EMB    2048
#define NH_    8
#define DH_    256
#define TOKENS 2048   // B*S
#define NBH    16     // B*NH
#define NQKVO  4736   // 2048 q | 256 k | 256 v | 2048 o | 8 i | 8 f | 112 pad

typedef __attribute__((ext_vector_type(4))) float    f32x4;
typedef __attribute__((ext_vector_type(8))) _Float16 f16x8;
typedef __attribute__((ext_vector_type(4))) _Float16 f16x4;

__device__ __forceinline__ _Float16 f2h(float f) { return (_Float16)f; }

// async global->LDS, 16B per lane; LDS dest = wave-uniform base + lane*16
__device__ __forceinline__ void gload16(const void* g, void* l) {
  __builtin_amdgcn_global_load_lds(
      (const __attribute__((address_space(1))) void*)g,
      (__attribute__((address_space(3))) void*)l, 16, 0, 0);
}

// ---------------------------------------------------------------------------
// Merged prep (one launch): x cast | big W transposes | Wi/Wf rows + pad.
// ---------------------------------------------------------------------------
__global__ __launch_bounds__(256) void prep_kernel(
    const float* __restrict__ x,
    const float* __restrict__ Wq, const float* __restrict__ Wk,
    const float* __restrict__ Wv, const float* __restrict__ Wog,
    const float* __restrict__ Wout,
    const float* __restrict__ Wi, const float* __restrict__ Wf,
    _Float16* __restrict__ xh,
    _Float16* __restrict__ WcatT, _Float16* __restrict__ WoutT)
{
  __shared__ float shmem[64][65];
  int t = blockIdx.x;
  const int tid = threadIdx.x;
  if (t < TOKENS) {
    const long base = (long)t * EMB + tid * 8;
    const float4 a = *(const float4*)(x + base);
    const float4 b = *(const float4*)(x + base + 4);
    f16x8 o = {f2h(a.x), f2h(a.y), f2h(a.z), f2h(a.w),
               f2h(b.x), f2h(b.y), f2h(b.z), f2h(b.w)};
    *(f16x8*)(xh + base) = o;
  } else if (t < TOKENS + 3328) {
    t -= TOKENS;
    const float* in; _Float16* out; int ldi, ct;
    if (t < 1024)      { in = Wq;   out = WcatT;                    ldi = 2048; ct = 32; }
    else if (t < 1152) { t -= 1024; in = Wk;  out = WcatT + (long)2048 * EMB; ldi = 256; ct = 4; }
    else if (t < 1280) { t -= 1152; in = Wv;  out = WcatT + (long)2304 * EMB; ldi = 256; ct = 4; }
    else if (t < 2304) { t -= 1280; in = Wog; out = WcatT + (long)2560 * EMB; ldi = 2048; ct = 32; }
    else               { t -= 2304; in = Wout; out = WoutT;         ldi = 2048; ct = 32; }
    const long c0 = (long)(t % ct) * 64, r0 = (long)(t / ct) * 64;
    const int lx = tid & 63, ly = tid >> 6;
    #pragma unroll
    for (int i = 0; i < 16; ++i)
      shmem[ly + i * 4][lx] = in[(r0 + ly + i * 4) * ldi + c0 + lx];
    __syncthreads();
    #pragma unroll
    for (int i = 0; i < 16; ++i)
      out[(c0 + ly + i * 4) * EMB + r0 + lx] = f2h(shmem[lx][ly + i * 4]);
  } else {
    const int j = t - (TOKENS + 3328);           // 0..63, 2 rows each
    const int row = 4608 + j * 2 + (tid >> 7);
    const int c0 = (tid & 127) * 16;
    _Float16* dst = WcatT + (long)row * EMB + c0;
    if (row < 4616) {
      const int jj = row - 4608;
      #pragma unroll
      for (int k = 0; k < 16; ++k) dst[k] = f2h(Wi[(long)(c0 + k) * 8 + jj]);
    } else if (row < 4624) {
      const int jj = row - 4616;
      #pragma unroll
      for (int k = 0; k < 16; ++k) dst[k] = f2h(Wf[(long)(c0 + k) * 8 + jj]);
    } else {
      #pragma unroll
      for (int k = 0; k < 16; ++k) dst[k] = (_Float16)0.0f;
    }
  }
}

// ---------------------------------------------------------------------------
// QKVO projection GEMM (R19): 128x128 tile, BK=64, 2-buffer, 512 threads /
// 8 waves (2x4), wave-tile 64x32 -> acc[4][2] (32 VGPR, light).
// R18's proven loop (stage BEFORE counted vmcnt, two barriers) with doubled
// per-barrier compute (16 MFMA/wave/step, nt=32).  64 KB LDS at 512 threads
// -> 2 blocks/CU = 4 waves/SIMD (MORE than the BK=32 config's 3 — avoids
// the m132 trap where BK growth at 256 thr cut occupancy).
// Swizzle (8 chunks/row): store slot^(row&7), read (kk*4+kseg)^(row&7).
// L = 4 loads/thread/stage -> vmcnt(4)/0.
// ---------------------------------------------------------------------------
__global__ __launch_bounds__(512, 4) void gemm_qkvo_kernel(
    const _Float16* __restrict__ Ag, const _Float16* __restrict__ Btg,
    _Float16* __restrict__ Cg, int K, int lda, int ldb, int ldc, int mtiles)
{
  __shared__ _Float16 As[2][128 * 64];
  __shared__ _Float16 Bs[2][128 * 64];
  const int tid = threadIdx.x;
  const int lane = tid & 63, wid = tid >> 6;       // 8 waves
  const int cpx = gridDim.x >> 3;
  const int wg = ((int)blockIdx.x & 7) * cpx + ((int)blockIdx.x >> 3);
  const int m0 = (wg % mtiles) * 128;
  const int n0 = (wg / mtiles) * 128;
  const _Float16* Ap = Ag + (long)m0 * lda;
  const _Float16* Bp = Btg + (long)n0 * ldb;
  const int wr = wid >> 2, wc = wid & 3;           // 2x4 wave grid
  const int lrow = lane & 15, kseg = lane >> 4;

  auto stage = [&](int b, int k0) {
    #pragma unroll
    for (int i = 0; i < 2; ++i) {                  // A: 1024 chunks (8/row)
      const int cbase = (i * 8 + wid) * 64;
      const int c = cbase + lane;
      const int row = c >> 3, slot = c & 7;
      gload16(Ap + (long)row * lda + k0 + (slot ^ (row & 7)) * 8,
              (char*)As[b] + cbase * 16);
    }
    #pragma unroll
    for (int i = 0; i < 2; ++i) {                  // B: 1024 chunks (8/row)
      const int cbase = (i * 8 + wid) * 64;
      const int c = cbase + lane;
      const int row = c >> 3, slot = c & 7;
      gload16(Bp + (long)row * ldb + k0 + (slot ^ (row & 7)) * 8,
              (char*)Bs[b] + cbase * 16);
    }
  };

  const int nt = K >> 6;                           // K-tiles of 64
  f32x4 acc[4][2] = {};
  stage(0, 0);
  int buf = 0;
  for (int t = 0; t < nt; ++t) {
    if (t + 1 < nt) {
      stage(buf ^ 1, (t + 1) * 64);                // prefetch next tile
      asm volatile("s_waitcnt vmcnt(4)" ::: "memory");  // t's 4 loads done
    } else {
      asm volatile("s_waitcnt vmcnt(0)" ::: "memory");
    }
    __builtin_amdgcn_s_barrier();
    __builtin_amdgcn_sched_barrier(0);
    #pragma unroll
    for (int kk = 0; kk < 2; ++kk) {               // two K=32 sub-steps
      f16x8 fa[4], fb[2];
      #pragma unroll
      for (int m = 0; m < 4; ++m) {
        const int row = wr * 64 + m * 16 + lrow;
        fa[m] = *(const f16x8*)&As[buf][row * 64 + (((kk * 4 + kseg) ^ (row & 7)) << 3)];
      }
      #pragma unroll
      for (int n = 0; n < 2; ++n) {
        const int row = wc * 32 + n * 16 + lrow;
        fb[n] = *(const f16x8*)&Bs[buf][row * 64 + (((kk * 4 + kseg) ^ (row & 7)) << 3)];
      }
      #pragma unroll
      for (int m = 0; m < 4; ++m)
        #pragma unroll
        for (int n = 0; n < 2; ++n)
          acc[m][n] = __builtin_amdgcn_mfma_f32_16x16x32_f16(fa[m], fb[n], acc[m][n], 0, 0, 0);
    }
    __builtin_amdgcn_s_barrier();
    buf ^= 1;
  }
  #pragma unroll
  for (int m = 0; m < 4; ++m)
    #pragma unroll
    for (int n = 0; n < 2; ++n)
      #pragma unroll
      for (int i = 0; i < 4; ++i) {
        const int r = m0 + wr * 64 + m * 16 + kseg * 4 + i;   // row=(lane>>4)*4+i (m89)
        const int c = n0 + wc * 32 + n * 16 + lrow;           // col=lane&15
        Cg[(long)r * ldc + c] = (_Float16)acc[m][n][i];
      }
}

// ---------------------------------------------------------------------------
// Output projection GEMM (R18): 64x128 tile, BK=64, 2-buffer, 4 waves.
// ---------------------------------------------------------------------------
__global__ __launch_bounds__(256) void gemm_out_kernel(
    const _Float16* __restrict__ Ag, const _Float16* __restrict__ Btg,
    float* __restrict__ Cg, int K, int lda, int ldb, int ldc, int mtiles)
{
  __shared__ _Float16 As[2][64 * 64];
  __shared__ _Float16 Bs[2][128 * 64];
  const int tid = threadIdx.x;
  const int lane = tid & 63, wid = tid >> 6;
  const int cpx = gridDim.x >> 3;
  const int wg = ((int)blockIdx.x & 7) * cpx + ((int)blockIdx.x >> 3);
  const int m0 = (wg % mtiles) * 64;
  const int n0 = (wg / mtiles) * 128;
  const _Float16* Ap = Ag + (long)m0 * lda;
  const _Float16* Bp = Btg + (long)n0 * ldb;
  const int wr = wid >> 1, wc = wid & 1;
  const int lrow = lane & 15, kseg = lane >> 4;

  auto stage = [&](int b, int k0) {
    #pragma unroll
    for (int i = 0; i < 2; ++i) {                 // A: 512 chunks (8/row)
      const int cbase = (i * 4 + wid) * 64;
      const int c = cbase + lane;
      const int row = c >> 3, slot = c & 7;
      gload16(Ap + (long)row * lda + k0 + (slot ^ (row & 7)) * 8,
              (char*)As[b] + cbase * 16);
    }
    #pragma unroll
    for (int i = 0; i < 4; ++i) {                 // B: 1024 chunks (8/row)
      const int cbase = (i * 4 + wid) * 64;
      const int c = cbase + lane;
      const int row = c >> 3, slot = c & 7;
      gload16(Bp + (long)row * ldb + k0 + (slot ^ (row & 7)) * 8,
              (char*)Bs[b] + cbase * 16);
    }
  };

  const int nt = K >> 6;                          // K-tiles of 64
  f32x4 acc[2][4] = {};
  stage(0, 0);
  int buf = 0;
  for (int t = 0; t < nt; ++t) {
    if (t + 1 < nt) {
      stage(buf ^ 1, (t + 1) * 64);               // prefetch next tile
      asm volatile("s_waitcnt vmcnt(6)" ::: "memory");  // t's 6 loads done
    } else {
      asm volatile("s_waitcnt vmcnt(0)" ::: "memory");
    }
    __builtin_amdgcn_s_barrier();
    __builtin_amdgcn_sched_barrier(0);
    #pragma unroll
    for (int kk = 0; kk < 2; ++kk) {              // two K=32 sub-steps
      f16x8 fa[2], fb[4];
      #pragma unroll
      for (int m = 0; m < 2; ++m) {
        const int row = wr * 32 + m * 16 + lrow;
        fa[m] = *(const f16x8*)&As[buf][row * 64 + (((kk * 4 + kseg) ^ (row & 7)) << 3)];
      }
      #pragma unroll
      for (int n = 0; n < 4; ++n) {
        const int row = wc * 64 + n * 16 + lrow;
        fb[n] = *(const f16x8*)&Bs[buf][row * 64 + (((kk * 4 + kseg) ^ (row & 7)) << 3)];
      }
      #pragma unroll
      for (int m = 0; m < 2; ++m)
        #pragma unroll
        for (int n = 0; n < 4; ++n)
          acc[m][n] = __builtin_amdgcn_mfma_f32_16x16x32_f16(fa[m], fb[n], acc[m][n], 0, 0, 0);
    }
    __builtin_amdgcn_s_barrier();
    buf ^= 1;
  }
  #pragma unroll
  for (int m = 0; m < 2; ++m)
    #pragma unroll
    for (int n = 0; n < 4; ++n)
      #pragma unroll
      for (int i = 0; i < 4; ++i) {
        const int r = m0 + wr * 32 + m * 16 + kseg * 4 + i;
        const int c = n0 + wc * 64 + n * 16 + lrow;
        Cg[(long)r * ldc + c] = acc[m][n][i];
      }
}

// ---------------------------------------------------------------------------
// Merged mid stage (one launch): gates (wave-scan, z from qkvo) + V^T.
// ---------------------------------------------------------------------------
__global__ __launch_bounds__(256) void mid_kernel(
    const _Float16* __restrict__ qkvo, _Float16* __restrict__ vt,
    const float* __restrict__ bi, const float* __restrict__ bfg,
    float* __restrict__ aArr, float* __restrict__ mArr, float* __restrict__ vMArr)
{
  __shared__ float shmem[64][65];
  const int tid = threadIdx.x;
  int t = blockIdx.x;
  if (t < NBH) {
    const int bh = t;
    const int b = bh >> 3, h = bh & 7;
    const int lane = tid & 63, wid = tid >> 6;
    float* wsum = &shmem[0][0];
    float* wmax = &shmem[1][0];
    const float bih = bi[h], bfh = bfg[h];
    const int s4 = tid * 4;
    const _Float16* zb = qkvo + (long)(b * S_LEN + s4) * NQKVO;
    float zf[4], zi[4];
    #pragma unroll
    for (int k = 0; k < 4; ++k) {
      zi[k] = 15.0f * tanhf(((float)zb[(long)k * NQKVO + 4608 + h] + bih) * (1.0f / 15.0f));
      zf[k] = 15.0f * tanhf(((float)zb[(long)k * NQKVO + 4616 + h] + bfh) * (1.0f / 15.0f));
    }
    float lg[4];
    #pragma unroll
    for (int k = 0; k < 4; ++k)
      lg[k] = fminf(zf[k], 0.0f) - log1pf(expf(-fabsf(zf[k])));
    float c0 = lg[0], c1 = c0 + lg[1], c2 = c1 + lg[2], c3 = c2 + lg[3];
    float ts = c3;
    #pragma unroll
    for (int off = 1; off < 64; off <<= 1) {
      const float o = __shfl_up(ts, off);
      if (lane >= off) ts += o;
    }
    const float texcl = ts - c3;
    if (lane == 63) wsum[wid] = ts;
    __syncthreads();
    float woff = 0.0f;
    for (int w = 0; w < wid; ++w) woff += wsum[w];
    const float base = woff + texcl;
    const float cf[4] = { base + c0, base + c1, base + c2, base + c3 };
    const float a[4] = { zi[0] - cf[0], zi[1] - cf[1], zi[2] - cf[2], zi[3] - cf[3] };
    float l1 = fmaxf(a[0], a[1]), l3 = fmaxf(fmaxf(l1, a[2]), a[3]);
    float incl = l3;
    #pragma unroll
    for (int off = 1; off < 64; off <<= 1) {
      const float o = __shfl_up(incl, off);
      if (lane >= off) incl = fmaxf(incl, o);
    }
    float excl = __shfl_up(incl, 1);
    if (lane == 0) excl = -3.0e38f;
    if (lane == 63) wmax[wid] = incl;
    __syncthreads();
    float wpre = -3.0e38f;
    for (int w = 0; w < wid; ++w) wpre = fmaxf(wpre, wmax[w]);
    const float pre = fmaxf(wpre, excl);
    float mm[4];
    mm[0] = fmaxf(pre, a[0]); mm[1] = fmaxf(mm[0], a[1]);
    mm[2] = fmaxf(mm[1], a[2]); mm[3] = fmaxf(mm[2], a[3]);
    float4 av = { a[0], a[1], a[2], a[3] };
    float4 mv = { mm[0], mm[1], mm[2], mm[3] };
    float4 vv = { cf[0] + mm[0], cf[1] + mm[1], cf[2] + mm[2], cf[3] + mm[3] };
    *(float4*)(aArr + (long)bh * S_LEN + s4) = av;
    *(float4*)(mArr + (long)bh * S_LEN + s4) = mv;
    *(float4*)(vMArr + (long)bh * S_LEN + s4) = vv;
  } else {
    t -= NBH;
    const int z = t >> 6, rem = t & 63;
    const long c0 = (long)(rem & 3) * 64;    // d-tile
    const long r0 = (long)(rem >> 2) * 64;   // s-tile
    const _Float16* ipt = qkvo + (long)z * S_LEN * NQKVO + 2304;
    _Float16* op = vt + (long)z * DH_ * S_LEN;
    const int lx = tid & 63, ly = tid >> 6;
    #pragma unroll
    for (int i = 0; i < 16; ++i)
      shmem[ly + i * 4][lx] = (float)ipt[(r0 + ly + i * 4) * NQKVO + c0 + lx];
    __syncthreads();
    #pragma unroll
    for (int i = 0; i < 16; ++i)
      op[(c0 + ly + i * 4) * S_LEN + r0 + lx] = f2h(shmem[lx][ly + i * 4]);
  }
}

// ---------------------------------------------------------------------------
// Fused mLSTM attention + LN + output gate, triangle-paired, QBLK=32,
// 512 threads / 8 waves (R11/R14 config).
// ---------------------------------------------------------------------------
__global__ __launch_bounds__(512) void att_fused_kernel(
    const _Float16* __restrict__ qkvo, const _Float16* __restrict__ vt,
    const float* __restrict__ aArr, const float* __restrict__ mArr,
    const float* __restrict__ vMArr, const float* __restrict__ gamma,
    _Float16* __restrict__ ub)
{
  __shared__ _Float16 Qs[2][32 * 256];   // swizzled: 32 chunks/row, ^(row&7)
  __shared__ _Float16 Ws[2][32 * 128];   // swizzled: 16 chunks/row, ^((row&7)<<1)
  __shared__ float nsh[2][8][32];
  __shared__ float s2sh[2][8][32];
  __shared__ float invs[2][32];
  __shared__ float musl[2][32], rssl[2][32];
  const int tid = threadIdx.x;
  const int lane = tid & 63, wid = tid >> 6;     // 8 waves
  const int bh = blockIdx.y;
  const int b = bh >> 3, h = bh & 7;
  const int r0[2] = { (int)blockIdx.x * 32, (31 - (int)blockIdx.x) * 32 };
  const _Float16* Qg = qkvo + (long)(b * S_LEN) * NQKVO + h * DH_;
  const _Float16* Kg = qkvo + (long)(b * S_LEN) * NQKVO + 2048;
  const _Float16* Og = qkvo + (long)(b * S_LEN) * NQKVO + 2560 + h * DH_;
  const _Float16* Vt = vt + (long)b * DH_ * S_LEN;
  const float* aA = aArr + (long)bh * S_LEN;
  const float* mA = mArr + (long)bh * S_LEN;
  const float* gam = gamma + h * DH_;
  const int lrow = lane & 15, kseg = lane >> 4;
  const int tbase = 16 * wid;                    // QK t-slice per wave
  const int dbase = 32 * wid;                    // PV d-slice per wave

  #pragma unroll
  for (int i = 0; i < 4; ++i) {
    const int cbase = (i * 8 + wid) * 64;        // wave-uniform
    const int c = cbase + lane;
    const int sub = c >> 10, row = (c >> 5) & 31, slot = c & 31;
    gload16(Qg + (long)(r0[sub] + row) * NQKVO + (slot ^ (row & 7)) * 8,
            (char*)Qs + cbase * 16);
  }

  float m_s[2][2][4];
  #pragma unroll
  for (int sub = 0; sub < 2; ++sub)
    #pragma unroll
    for (int m = 0; m < 2; ++m)
      #pragma unroll
      for (int i = 0; i < 4; ++i)
        m_s[sub][m][i] = mA[r0[sub] + m * 16 + kseg * 4 + i];
  __syncthreads();   // Q staged (drains vmcnt)

  f32x4 hacc[2][2][2] = {};
  float nacc[2][2][4] = {};
  for (int n0 = 0; n0 <= r0[1]; n0 += 128) {
    f32x4 acc[2][2] = {};
    f16x8 fb, fbn;
    fb = *(const f16x8*)(Kg + (long)(n0 + tbase + lrow) * NQKVO + kseg * 8);
    #pragma unroll
    for (int k0 = 0; k0 < DH_; k0 += 32) {
      if (k0 + 32 < DH_)
        fbn = *(const f16x8*)(Kg + (long)(n0 + tbase + lrow) * NQKVO + k0 + 32 + kseg * 8);
      const int chunk = (k0 >> 3) + kseg;
      __builtin_amdgcn_s_setprio(1);
      #pragma unroll
      for (int sub = 0; sub < 2; ++sub) {
        if (n0 > r0[sub]) continue;
        #pragma unroll
        for (int m = 0; m < 2; ++m) {
          const int qrow = m * 16 + lrow;
          const f16x8 fa = *(const f16x8*)&Qs[sub][qrow * 256 + ((chunk ^ (qrow & 7)) << 3)];
          acc[sub][m] = __builtin_amdgcn_mfma_f32_16x16x32_f16(fa, fb, acc[sub][m], 0, 0, 0);
        }
      }
      __builtin_amdgcn_s_setprio(0);
      fb = fbn;
    }
    const float a_t = aA[n0 + tbase + lrow];
    #pragma unroll
    for (int sub = 0; sub < 2; ++sub) {
      if (n0 > r0[sub]) continue;
      #pragma unroll
      for (int m = 0; m < 2; ++m)
        #pragma unroll
        for (int i = 0; i < 4; ++i) {
          const int sr = m * 16 + kseg * 4 + i;     // local row 0..31
          const int t  = tbase + lrow;              // local col 0..127
          float w = 0.0f;
          if (n0 + t <= r0[sub] + sr)
            w = acc[sub][m][i] * 0.0625f * expf(a_t - m_s[sub][m][i]);
          nacc[sub][m][i] += w;
          Ws[sub][sr * 128 + (((t >> 3) ^ ((sr & 7) << 1)) << 3) + (t & 7)] = f2h(w);
        }
    }
    f16x8 vb[2], vbn[2];
    #pragma unroll
    for (int n = 0; n < 2; ++n)
      vb[n] = *(const f16x8*)(Vt + (long)(dbase + n * 16 + lrow) * S_LEN + n0 + kseg * 8);
    __syncthreads();
    #pragma unroll
    for (int kt = 0; kt < 128; kt += 32) {
      if (kt + 32 < 128) {
        #pragma unroll
        for (int n = 0; n < 2; ++n)
          vbn[n] = *(const f16x8*)(Vt + (long)(dbase + n * 16 + lrow) * S_LEN + n0 + kt + 32 + kseg * 8);
      }
      const int chunk = (kt >> 3) + kseg;
      __builtin_amdgcn_s_setprio(1);
      #pragma unroll
      for (int sub = 0; sub < 2; ++sub) {
        if (n0 > r0[sub]) continue;
        #pragma unroll
        for (int m = 0; m < 2; ++m) {
          const int row = m * 16 + lrow;
          const f16x8 wa = *(const f16x8*)&Ws[sub][row * 128 + ((chunk ^ ((row & 7) << 1)) << 3)];
          #pragma unroll
          for (int n = 0; n < 2; ++n)
            hacc[sub][m][n] = __builtin_amdgcn_mfma_f32_16x16x32_f16(wa, vb[n], hacc[sub][m][n], 0, 0, 0);
        }
      }
      __builtin_amdgcn_s_setprio(0);
      vb[0] = vbn[0]; vb[1] = vbn[1];
    }
    __syncthreads();   // Ws reads done before next pass overwrites
  }
  #pragma unroll
  for (int sub = 0; sub < 2; ++sub)
    #pragma unroll
    for (int m = 0; m < 2; ++m)
      #pragma unroll
      for (int i = 0; i < 4; ++i) {
        float v = nacc[sub][m][i];
        v += __shfl_xor(v, 1); v += __shfl_xor(v, 2);
        v += __shfl_xor(v, 4); v += __shfl_xor(v, 8);
        if (lrow == 0) nsh[sub][wid][m * 16 + kseg * 4 + i] = v;
      }
  __syncthreads();
  if (tid < 64) {
    const int sub = tid >> 5, sr = tid & 31;
    float tot = 0.0f;
    #pragma unroll
    for (int w = 0; w < 8; ++w) tot += nsh[sub][w][sr];
    const float vm = vMArr[(long)bh * S_LEN + r0[sub] + sr];
    const float vecN = fmaxf(fabsf(tot), expf(-vm));
    invs[sub][sr] = 1.0f / (vecN + 1e-6f);
  }
  __syncthreads();
  #pragma unroll
  for (int sub = 0; sub < 2; ++sub)
    #pragma unroll
    for (int m = 0; m < 2; ++m)
      #pragma unroll
      for (int i = 0; i < 4; ++i) {
        const int row = m * 16 + kseg * 4 + i;
        const float inv = invs[sub][row];
        hacc[sub][m][0][i] *= inv;
        hacc[sub][m][1][i] *= inv;
        float s1 = hacc[sub][m][0][i] + hacc[sub][m][1][i];
        float s2 = hacc[sub][m][0][i] * hacc[sub][m][0][i]
                 + hacc[sub][m][1][i] * hacc[sub][m][1][i];
        s1 += __shfl_xor(s1, 1); s2 += __shfl_xor(s2, 1);
        s1 += __shfl_xor(s1, 2); s2 += __shfl_xor(s2, 2);
        s1 += __shfl_xor(s1, 4); s2 += __shfl_xor(s2, 4);
        s1 += __shfl_xor(s1, 8); s2 += __shfl_xor(s2, 8);
        if (lrow == 0) { nsh[sub][wid][row] = s1; s2sh[sub][wid][row] = s2; }
      }
  __syncthreads();
  if (tid < 64) {
    const int sub = tid >> 5, sr = tid & 31;
    float s1 = 0.0f, s2 = 0.0f;
    #pragma unroll
    for (int w = 0; w < 8; ++w) { s1 += nsh[sub][w][sr]; s2 += s2sh[sub][w][sr]; }
    const float mu = s1 * (1.0f / 256.0f);
    const float var = s2 * (1.0f / 256.0f) - mu * mu;
    musl[sub][sr] = mu;
    rssl[sub][sr] = rsqrtf(var + 1e-6f);
  }
  __syncthreads();
  #pragma unroll
  for (int sub = 0; sub < 2; ++sub)
    #pragma unroll
    for (int m = 0; m < 2; ++m)
      #pragma unroll
      for (int n = 0; n < 2; ++n)
        #pragma unroll
        for (int i = 0; i < 4; ++i) {
          const int row = m * 16 + kseg * 4 + i;
          const int d = dbase + n * 16 + lrow;
          const long gr = r0[sub] + row;
          const float hn = (hacc[sub][m][n][i] - musl[sub][row]) * rssl[sub][row] * gam[d];
          const float o = (float)Og[((long)gr) * NQKVO + d];
          ub[(long)(b * S_LEN + gr) * EMB + h * DH_ + d] =
              f2h(hn * (1.0f / (1.0f + expf(-o))));
        }
}

// ---------------------------------------------------------------------------
extern "C" void kernel_launch(void* const* d_in, const int* in_sizes, int n_in,
                              void* d_out, int out_size, void* d_ws, size_t ws_size,
                              hipStream_t stream)
{
  (void)in_sizes; (void)n_in; (void)out_size; (void)ws_size;
  const float* x     = (const float*)d_in[0];
  const float* Wq    = (const float*)d_in[1];
  const float* Wk    = (const float*)d_in[2];
  const float* Wv    = (const float*)d_in[3];
  const float* Wog   = (const float*)d_in[4];
  const float* Wi    = (const float*)d_in[5];
  const float* bi    = (const float*)d_in[6];
  const float* Wf    = (const float*)d_in[7];
  const float* bfg   = (const float*)d_in[8];
  const float* gamma = (const float*)d_in[9];
  const float* Wout  = (const float*)d_in[10];

  char* base = (char*)d_ws;
  size_t off = 0;
  auto take = [&](size_t bytes) -> char* {
    char* p = base + off;
    off += (bytes + 255) & ~(size_t)255;
    return p;
  };
  _Float16* xh    = (_Float16*)take((size_t)TOKENS * EMB * 2);        //  8 MB
  _Float16* WcatT = (_Float16*)take((size_t)NQKVO * EMB * 2);         // 19.4 MB
  _Float16* WoutT = (_Float16*)take((size_t)EMB * EMB * 2);           //  8 MB
  _Float16* qkvo  = (_Float16*)take((size_t)TOKENS * NQKVO * 2);      // 19.4 MB
  _Float16* vt    = (_Float16*)take((size_t)2 * DH_ * S_LEN * 2);     //  1 MB
  _Float16* ub    = (_Float16*)take((size_t)TOKENS * EMB * 2);        //  8 MB
  float*    aA    = (float*)take((size_t)NBH * S_LEN * 4);
  float*    mA    = (float*)take((size_t)NBH * S_LEN * 4);
  float*    vM    = (float*)take((size_t)NBH * S_LEN * 4);
  float*    y     = (float*)d_out;

  const dim3 blk(256);
  // --- merged prep: x cast + all weight transposes + i/f rows (1 launch) ---
  prep_kernel<<<dim3(TOKENS + 3328 + 64), blk, 0, stream>>>(
      x, Wq, Wk, Wv, Wog, Wout, Wi, Wf, xh, WcatT, WoutT);
  // --- fused QKVO+if projection: BK=64 2-buf, 512 thr (R19) ---
  gemm_qkvo_kernel<<<dim3(16 * 37), dim3(512), 0, stream>>>(
      xh, WcatT, qkvo, EMB, EMB, EMB, NQKVO, 16);
  // --- merged mid: gates (from qkvo z-cols) + V^T transpose ---
  mid_kernel<<<dim3(NBH + 128), blk, 0, stream>>>(qkvo, vt, bi, bfg, aA, mA, vM);
  // --- fused mLSTM backend + LN + output gate (writes ub directly) ---
  att_fused_kernel<<<dim3(16, NBH), dim3(512), 0, stream>>>(
      qkvo, vt, aA, mA, vM, gamma, ub);
  // --- output projection: BM=64/BK=64 2-buf, 512 blocks (R18) ---
  gemm_out_kernel<<<dim3(32 * 16), blk, 0, stream>>>(
      ub, WoutT, y, EMB, EMB, EMB, EMB, 32);
}

// Round 20
// 159.464 us; speedup vs baseline: 1.0692x; 1.0692x over previous
//
#include <hip/hip_runtime.h>
#include <math.h>

#define S_LEN  1024
#define EMB    2048
#define NH_    8
#define DH_    256
#define TOKENS 2048   // B*S
#define NBH    16     // B*NH
#define NQKVO  4736   // 2048 q | 256 k | 256 v | 2048 o | 8 i | 8 f | 112 pad

typedef __attribute__((ext_vector_type(4))) float    f32x4;
typedef __attribute__((ext_vector_type(8))) _Float16 f16x8;
typedef __attribute__((ext_vector_type(4))) _Float16 f16x4;

__device__ __forceinline__ _Float16 f2h(float f) { return (_Float16)f; }

// async global->LDS, 16B per lane; LDS dest = wave-uniform base + lane*16
__device__ __forceinline__ void gload16(const void* g, void* l) {
  __builtin_amdgcn_global_load_lds(
      (const __attribute__((address_space(1))) void*)g,
      (__attribute__((address_space(3))) void*)l, 16, 0, 0);
}

// ---------------------------------------------------------------------------
// Merged prep (one launch): x cast | big W transposes | Wi/Wf rows + pad.
// ---------------------------------------------------------------------------
__global__ __launch_bounds__(256) void prep_kernel(
    const float* __restrict__ x,
    const float* __restrict__ Wq, const float* __restrict__ Wk,
    const float* __restrict__ Wv, const float* __restrict__ Wog,
    const float* __restrict__ Wout,
    const float* __restrict__ Wi, const float* __restrict__ Wf,
    _Float16* __restrict__ xh,
    _Float16* __restrict__ WcatT, _Float16* __restrict__ WoutT)
{
  __shared__ float shmem[64][65];
  int t = blockIdx.x;
  const int tid = threadIdx.x;
  if (t < TOKENS) {
    const long base = (long)t * EMB + tid * 8;
    const float4 a = *(const float4*)(x + base);
    const float4 b = *(const float4*)(x + base + 4);
    f16x8 o = {f2h(a.x), f2h(a.y), f2h(a.z), f2h(a.w),
               f2h(b.x), f2h(b.y), f2h(b.z), f2h(b.w)};
    *(f16x8*)(xh + base) = o;
  } else if (t < TOKENS + 3328) {
    t -= TOKENS;
    const float* in; _Float16* out; int ldi, ct;
    if (t < 1024)      { in = Wq;   out = WcatT;                    ldi = 2048; ct = 32; }
    else if (t < 1152) { t -= 1024; in = Wk;  out = WcatT + (long)2048 * EMB; ldi = 256; ct = 4; }
    else if (t < 1280) { t -= 1152; in = Wv;  out = WcatT + (long)2304 * EMB; ldi = 256; ct = 4; }
    else if (t < 2304) { t -= 1280; in = Wog; out = WcatT + (long)2560 * EMB; ldi = 2048; ct = 32; }
    else               { t -= 2304; in = Wout; out = WoutT;         ldi = 2048; ct = 32; }
    const long c0 = (long)(t % ct) * 64, r0 = (long)(t / ct) * 64;
    const int lx = tid & 63, ly = tid >> 6;
    #pragma unroll
    for (int i = 0; i < 16; ++i)
      shmem[ly + i * 4][lx] = in[(r0 + ly + i * 4) * ldi + c0 + lx];
    __syncthreads();
    #pragma unroll
    for (int i = 0; i < 16; ++i)
      out[(c0 + ly + i * 4) * EMB + r0 + lx] = f2h(shmem[lx][ly + i * 4]);
  } else {
    const int j = t - (TOKENS + 3328);           // 0..63, 2 rows each
    const int row = 4608 + j * 2 + (tid >> 7);
    const int c0 = (tid & 127) * 16;
    _Float16* dst = WcatT + (long)row * EMB + c0;
    if (row < 4616) {
      const int jj = row - 4608;
      #pragma unroll
      for (int k = 0; k < 16; ++k) dst[k] = f2h(Wi[(long)(c0 + k) * 8 + jj]);
    } else if (row < 4624) {
      const int jj = row - 4616;
      #pragma unroll
      for (int k = 0; k < 16; ++k) dst[k] = f2h(Wf[(long)(c0 + k) * 8 + jj]);
    } else {
      #pragma unroll
      for (int k = 0; k < 16; ++k) dst[k] = (_Float16)0.0f;
    }
  }
}

// ---------------------------------------------------------------------------
// f16 GEMM, BMx128 tile, BK=32, 4 waves, 3-deep prefetch (R12-proven loop).
// Used for the QKVO+if projection.
// ---------------------------------------------------------------------------
template<typename CT, int BM>
__global__ __launch_bounds__(256) void gemm_bt_kernel(
    const _Float16* __restrict__ Ag, const _Float16* __restrict__ Btg,
    CT* __restrict__ Cg, int K, int lda, int ldb, int ldc, int mtiles)
{
  constexpr int MR = BM / 32;
  __shared__ _Float16 As[3][BM * 32];
  __shared__ _Float16 Bs[3][128 * 32];
  const int tid = threadIdx.x;
  const int lane = tid & 63, wid = tid >> 6;
  const int cpx = gridDim.x >> 3;
  const int wg = ((int)blockIdx.x & 7) * cpx + ((int)blockIdx.x >> 3);
  const int m0 = (wg % mtiles) * BM;
  const int n0 = (wg / mtiles) * 128;
  const _Float16* Ap = Ag + (long)m0 * lda;
  const _Float16* Bp = Btg + (long)n0 * ldb;
  const int wr = wid >> 1, wc = wid & 1;
  const int lrow = lane & 15, kseg = lane >> 4;

  auto stage = [&](int b, int k0) {
    #pragma unroll
    for (int i = 0; i < BM / 64; ++i) {
      const int cbase = (i * 4 + wid) * 64;
      const int row = (cbase >> 2) + (lane >> 2);
      const int src = ((lane & 3) ^ ((row >> 1) & 3)) * 8;
      gload16(Ap + (long)row * lda + k0 + src, (char*)As[b] + cbase * 16);
    }
    #pragma unroll
    for (int i = 0; i < 2; ++i) {
      const int cbase = (i * 4 + wid) * 64;
      const int row = (cbase >> 2) + (lane >> 2);
      const int src = ((lane & 3) ^ ((row >> 1) & 3)) * 8;
      gload16(Bp + (long)row * ldb + k0 + src, (char*)Bs[b] + cbase * 16);
    }
  };

  const int nt = K >> 5;
  f32x4 acc[MR][4] = {};
  stage(0, 0);
  if (nt > 1) stage(1, 32);
  for (int t = 0; t < nt; ++t) {
    if (t + 2 < nt) {
      stage((t + 2) % 3, (t + 2) * 32);
      if constexpr (BM == 128) asm volatile("s_waitcnt vmcnt(8)" ::: "memory");
      else                     asm volatile("s_waitcnt vmcnt(6)" ::: "memory");
    } else if (t + 1 < nt) {
      if constexpr (BM == 128) asm volatile("s_waitcnt vmcnt(4)" ::: "memory");
      else                     asm volatile("s_waitcnt vmcnt(3)" ::: "memory");
    } else {
      asm volatile("s_waitcnt vmcnt(0)" ::: "memory");
    }
    __builtin_amdgcn_s_barrier();
    __builtin_amdgcn_sched_barrier(0);
    const int buf = t % 3;
    f16x8 fa[MR], fb[4];
    #pragma unroll
    for (int m = 0; m < MR; ++m) {
      const int row = wr * (BM / 2) + m * 16 + lrow;
      fa[m] = *(const f16x8*)&As[buf][row * 32 + ((kseg ^ ((row >> 1) & 3)) << 3)];
    }
    #pragma unroll
    for (int n = 0; n < 4; ++n) {
      const int row = wc * 64 + n * 16 + lrow;
      fb[n] = *(const f16x8*)&Bs[buf][row * 32 + ((kseg ^ ((row >> 1) & 3)) << 3)];
    }
    #pragma unroll
    for (int m = 0; m < MR; ++m)
      #pragma unroll
      for (int n = 0; n < 4; ++n)
        acc[m][n] = __builtin_amdgcn_mfma_f32_16x16x32_f16(fa[m], fb[n], acc[m][n], 0, 0, 0);
    __builtin_amdgcn_s_barrier();
  }
  #pragma unroll
  for (int m = 0; m < MR; ++m)
    #pragma unroll
    for (int n = 0; n < 4; ++n)
      #pragma unroll
      for (int i = 0; i < 4; ++i) {
        const int r = m0 + wr * (BM / 2) + m * 16 + kseg * 4 + i;  // row=(lane>>4)*4+i (m89)
        const int c = n0 + wc * 64 + n * 16 + lrow;                // col=lane&15
        Cg[(long)r * ldc + c] = (CT)acc[m][n][i];
      }
}

// ---------------------------------------------------------------------------
// Output projection GEMM (R18): 64x128 tile, BK=64, 2-buffer, 4 waves.
// 16 MFMA/wave per barrier-pair, nt=32 steps, 49 KB LDS -> 3 blocks/CU,
// grid 512.  Swizzle (8 chunks/row): store slot^(row&7), read
// (kk*4+kseg)^(row&7).  L = 6 loads/thread/stage -> vmcnt(6)/0.
// ---------------------------------------------------------------------------
__global__ __launch_bounds__(256) void gemm_out_kernel(
    const _Float16* __restrict__ Ag, const _Float16* __restrict__ Btg,
    float* __restrict__ Cg, int K, int lda, int ldb, int ldc, int mtiles)
{
  __shared__ _Float16 As[2][64 * 64];
  __shared__ _Float16 Bs[2][128 * 64];
  const int tid = threadIdx.x;
  const int lane = tid & 63, wid = tid >> 6;
  const int cpx = gridDim.x >> 3;
  const int wg = ((int)blockIdx.x & 7) * cpx + ((int)blockIdx.x >> 3);
  const int m0 = (wg % mtiles) * 64;
  const int n0 = (wg / mtiles) * 128;
  const _Float16* Ap = Ag + (long)m0 * lda;
  const _Float16* Bp = Btg + (long)n0 * ldb;
  const int wr = wid >> 1, wc = wid & 1;
  const int lrow = lane & 15, kseg = lane >> 4;

  auto stage = [&](int b, int k0) {
    #pragma unroll
    for (int i = 0; i < 2; ++i) {                 // A: 512 chunks (8/row)
      const int cbase = (i * 4 + wid) * 64;
      const int c = cbase + lane;
      const int row = c >> 3, slot = c & 7;
      gload16(Ap + (long)row * lda + k0 + (slot ^ (row & 7)) * 8,
              (char*)As[b] + cbase * 16);
    }
    #pragma unroll
    for (int i = 0; i < 4; ++i) {                 // B: 1024 chunks (8/row)
      const int cbase = (i * 4 + wid) * 64;
      const int c = cbase + lane;
      const int row = c >> 3, slot = c & 7;
      gload16(Bp + (long)row * ldb + k0 + (slot ^ (row & 7)) * 8,
              (char*)Bs[b] + cbase * 16);
    }
  };

  const int nt = K >> 6;                          // K-tiles of 64
  f32x4 acc[2][4] = {};
  stage(0, 0);
  int buf = 0;
  for (int t = 0; t < nt; ++t) {
    if (t + 1 < nt) {
      stage(buf ^ 1, (t + 1) * 64);               // prefetch next tile
      asm volatile("s_waitcnt vmcnt(6)" ::: "memory");  // t's 6 loads done
    } else {
      asm volatile("s_waitcnt vmcnt(0)" ::: "memory");
    }
    __builtin_amdgcn_s_barrier();
    __builtin_amdgcn_sched_barrier(0);
    #pragma unroll
    for (int kk = 0; kk < 2; ++kk) {              // two K=32 sub-steps
      f16x8 fa[2], fb[4];
      #pragma unroll
      for (int m = 0; m < 2; ++m) {
        const int row = wr * 32 + m * 16 + lrow;
        fa[m] = *(const f16x8*)&As[buf][row * 64 + (((kk * 4 + kseg) ^ (row & 7)) << 3)];
      }
      #pragma unroll
      for (int n = 0; n < 4; ++n) {
        const int row = wc * 64 + n * 16 + lrow;
        fb[n] = *(const f16x8*)&Bs[buf][row * 64 + (((kk * 4 + kseg) ^ (row & 7)) << 3)];
      }
      #pragma unroll
      for (int m = 0; m < 2; ++m)
        #pragma unroll
        for (int n = 0; n < 4; ++n)
          acc[m][n] = __builtin_amdgcn_mfma_f32_16x16x32_f16(fa[m], fb[n], acc[m][n], 0, 0, 0);
    }
    __builtin_amdgcn_s_barrier();
    buf ^= 1;
  }
  #pragma unroll
  for (int m = 0; m < 2; ++m)
    #pragma unroll
    for (int n = 0; n < 4; ++n)
      #pragma unroll
      for (int i = 0; i < 4; ++i) {
        const int r = m0 + wr * 32 + m * 16 + kseg * 4 + i;
        const int c = n0 + wc * 64 + n * 16 + lrow;
        Cg[(long)r * ldc + c] = acc[m][n][i];
      }
}

// ---------------------------------------------------------------------------
// Merged mid stage (one launch): gates (wave-scan, z from qkvo) + V^T.
// ---------------------------------------------------------------------------
__global__ __launch_bounds__(256) void mid_kernel(
    const _Float16* __restrict__ qkvo, _Float16* __restrict__ vt,
    const float* __restrict__ bi, const float* __restrict__ bfg,
    float* __restrict__ aArr, float* __restrict__ mArr, float* __restrict__ vMArr)
{
  __shared__ float shmem[64][65];
  const int tid = threadIdx.x;
  int t = blockIdx.x;
  if (t < NBH) {
    const int bh = t;
    const int b = bh >> 3, h = bh & 7;
    const int lane = tid & 63, wid = tid >> 6;
    float* wsum = &shmem[0][0];
    float* wmax = &shmem[1][0];
    const float bih = bi[h], bfh = bfg[h];
    const int s4 = tid * 4;
    const _Float16* zb = qkvo + (long)(b * S_LEN + s4) * NQKVO;
    float zf[4], zi[4];
    #pragma unroll
    for (int k = 0; k < 4; ++k) {
      zi[k] = 15.0f * tanhf(((float)zb[(long)k * NQKVO + 4608 + h] + bih) * (1.0f / 15.0f));
      zf[k] = 15.0f * tanhf(((float)zb[(long)k * NQKVO + 4616 + h] + bfh) * (1.0f / 15.0f));
    }
    float lg[4];
    #pragma unroll
    for (int k = 0; k < 4; ++k)
      lg[k] = fminf(zf[k], 0.0f) - log1pf(expf(-fabsf(zf[k])));
    float c0 = lg[0], c1 = c0 + lg[1], c2 = c1 + lg[2], c3 = c2 + lg[3];
    float ts = c3;
    #pragma unroll
    for (int off = 1; off < 64; off <<= 1) {
      const float o = __shfl_up(ts, off);
      if (lane >= off) ts += o;
    }
    const float texcl = ts - c3;
    if (lane == 63) wsum[wid] = ts;
    __syncthreads();
    float woff = 0.0f;
    for (int w = 0; w < wid; ++w) woff += wsum[w];
    const float base = woff + texcl;
    const float cf[4] = { base + c0, base + c1, base + c2, base + c3 };
    const float a[4] = { zi[0] - cf[0], zi[1] - cf[1], zi[2] - cf[2], zi[3] - cf[3] };
    float l1 = fmaxf(a[0], a[1]), l3 = fmaxf(fmaxf(l1, a[2]), a[3]);
    float incl = l3;
    #pragma unroll
    for (int off = 1; off < 64; off <<= 1) {
      const float o = __shfl_up(incl, off);
      if (lane >= off) incl = fmaxf(incl, o);
    }
    float excl = __shfl_up(incl, 1);
    if (lane == 0) excl = -3.0e38f;
    if (lane == 63) wmax[wid] = incl;
    __syncthreads();
    float wpre = -3.0e38f;
    for (int w = 0; w < wid; ++w) wpre = fmaxf(wpre, wmax[w]);
    const float pre = fmaxf(wpre, excl);
    float mm[4];
    mm[0] = fmaxf(pre, a[0]); mm[1] = fmaxf(mm[0], a[1]);
    mm[2] = fmaxf(mm[1], a[2]); mm[3] = fmaxf(mm[2], a[3]);
    float4 av = { a[0], a[1], a[2], a[3] };
    float4 mv = { mm[0], mm[1], mm[2], mm[3] };
    float4 vv = { cf[0] + mm[0], cf[1] + mm[1], cf[2] + mm[2], cf[3] + mm[3] };
    *(float4*)(aArr + (long)bh * S_LEN + s4) = av;
    *(float4*)(mArr + (long)bh * S_LEN + s4) = mv;
    *(float4*)(vMArr + (long)bh * S_LEN + s4) = vv;
  } else {
    t -= NBH;
    const int z = t >> 6, rem = t & 63;
    const long c0 = (long)(rem & 3) * 64;    // d-tile
    const long r0 = (long)(rem >> 2) * 64;   // s-tile
    const _Float16* ipt = qkvo + (long)z * S_LEN * NQKVO + 2304;
    _Float16* op = vt + (long)z * DH_ * S_LEN;
    const int lx = tid & 63, ly = tid >> 6;
    #pragma unroll
    for (int i = 0; i < 16; ++i)
      shmem[ly + i * 4][lx] = (float)ipt[(r0 + ly + i * 4) * NQKVO + c0 + lx];
    __syncthreads();
    #pragma unroll
    for (int i = 0; i < 16; ++i)
      op[(c0 + ly + i * 4) * S_LEN + r0 + lx] = f2h(shmem[lx][ly + i * 4]);
  }
}

// ---------------------------------------------------------------------------
// Fused mLSTM attention + LN + output gate, triangle-paired, QBLK=32,
// 512 threads / 8 waves (R11/R14 config).
// ---------------------------------------------------------------------------
__global__ __launch_bounds__(512) void att_fused_kernel(
    const _Float16* __restrict__ qkvo, const _Float16* __restrict__ vt,
    const float* __restrict__ aArr, const float* __restrict__ mArr,
    const float* __restrict__ vMArr, const float* __restrict__ gamma,
    _Float16* __restrict__ ub)
{
  __shared__ _Float16 Qs[2][32 * 256];   // swizzled: 32 chunks/row, ^(row&7)
  __shared__ _Float16 Ws[2][32 * 128];   // swizzled: 16 chunks/row, ^((row&7)<<1)
  __shared__ float nsh[2][8][32];
  __shared__ float s2sh[2][8][32];
  __shared__ float invs[2][32];
  __shared__ float musl[2][32], rssl[2][32];
  const int tid = threadIdx.x;
  const int lane = tid & 63, wid = tid >> 6;     // 8 waves
  const int bh = blockIdx.y;
  const int b = bh >> 3, h = bh & 7;
  const int r0[2] = { (int)blockIdx.x * 32, (31 - (int)blockIdx.x) * 32 };
  const _Float16* Qg = qkvo + (long)(b * S_LEN) * NQKVO + h * DH_;
  const _Float16* Kg = qkvo + (long)(b * S_LEN) * NQKVO + 2048;
  const _Float16* Og = qkvo + (long)(b * S_LEN) * NQKVO + 2560 + h * DH_;
  const _Float16* Vt = vt + (long)b * DH_ * S_LEN;
  const float* aA = aArr + (long)bh * S_LEN;
  const float* mA = mArr + (long)bh * S_LEN;
  const float* gam = gamma + h * DH_;
  const int lrow = lane & 15, kseg = lane >> 4;
  const int tbase = 16 * wid;                    // QK t-slice per wave
  const int dbase = 32 * wid;                    // PV d-slice per wave

  #pragma unroll
  for (int i = 0; i < 4; ++i) {
    const int cbase = (i * 8 + wid) * 64;        // wave-uniform
    const int c = cbase + lane;
    const int sub = c >> 10, row = (c >> 5) & 31, slot = c & 31;
    gload16(Qg + (long)(r0[sub] + row) * NQKVO + (slot ^ (row & 7)) * 8,
            (char*)Qs + cbase * 16);
  }

  float m_s[2][2][4];
  #pragma unroll
  for (int sub = 0; sub < 2; ++sub)
    #pragma unroll
    for (int m = 0; m < 2; ++m)
      #pragma unroll
      for (int i = 0; i < 4; ++i)
        m_s[sub][m][i] = mA[r0[sub] + m * 16 + kseg * 4 + i];
  __syncthreads();   // Q staged (drains vmcnt)

  f32x4 hacc[2][2][2] = {};
  float nacc[2][2][4] = {};
  for (int n0 = 0; n0 <= r0[1]; n0 += 128) {
    f32x4 acc[2][2] = {};
    f16x8 fb, fbn;
    fb = *(const f16x8*)(Kg + (long)(n0 + tbase + lrow) * NQKVO + kseg * 8);
    #pragma unroll
    for (int k0 = 0; k0 < DH_; k0 += 32) {
      if (k0 + 32 < DH_)
        fbn = *(const f16x8*)(Kg + (long)(n0 + tbase + lrow) * NQKVO + k0 + 32 + kseg * 8);
      const int chunk = (k0 >> 3) + kseg;
      __builtin_amdgcn_s_setprio(1);
      #pragma unroll
      for (int sub = 0; sub < 2; ++sub) {
        if (n0 > r0[sub]) continue;
        #pragma unroll
        for (int m = 0; m < 2; ++m) {
          const int qrow = m * 16 + lrow;
          const f16x8 fa = *(const f16x8*)&Qs[sub][qrow * 256 + ((chunk ^ (qrow & 7)) << 3)];
          acc[sub][m] = __builtin_amdgcn_mfma_f32_16x16x32_f16(fa, fb, acc[sub][m], 0, 0, 0);
        }
      }
      __builtin_amdgcn_s_setprio(0);
      fb = fbn;
    }
    const float a_t = aA[n0 + tbase + lrow];
    #pragma unroll
    for (int sub = 0; sub < 2; ++sub) {
      if (n0 > r0[sub]) continue;
      #pragma unroll
      for (int m = 0; m < 2; ++m)
        #pragma unroll
        for (int i = 0; i < 4; ++i) {
          const int sr = m * 16 + kseg * 4 + i;     // local row 0..31
          const int t  = tbase + lrow;              // local col 0..127
          float w = 0.0f;
          if (n0 + t <= r0[sub] + sr)
            w = acc[sub][m][i] * 0.0625f * expf(a_t - m_s[sub][m][i]);
          nacc[sub][m][i] += w;
          Ws[sub][sr * 128 + (((t >> 3) ^ ((sr & 7) << 1)) << 3) + (t & 7)] = f2h(w);
        }
    }
    f16x8 vb[2], vbn[2];
    #pragma unroll
    for (int n = 0; n < 2; ++n)
      vb[n] = *(const f16x8*)(Vt + (long)(dbase + n * 16 + lrow) * S_LEN + n0 + kseg * 8);
    __syncthreads();
    #pragma unroll
    for (int kt = 0; kt < 128; kt += 32) {
      if (kt + 32 < 128) {
        #pragma unroll
        for (int n = 0; n < 2; ++n)
          vbn[n] = *(const f16x8*)(Vt + (long)(dbase + n * 16 + lrow) * S_LEN + n0 + kt + 32 + kseg * 8);
      }
      const int chunk = (kt >> 3) + kseg;
      __builtin_amdgcn_s_setprio(1);
      #pragma unroll
      for (int sub = 0; sub < 2; ++sub) {
        if (n0 > r0[sub]) continue;
        #pragma unroll
        for (int m = 0; m < 2; ++m) {
          const int row = m * 16 + lrow;
          const f16x8 wa = *(const f16x8*)&Ws[sub][row * 128 + ((chunk ^ ((row & 7) << 1)) << 3)];
          #pragma unroll
          for (int n = 0; n < 2; ++n)
            hacc[sub][m][n] = __builtin_amdgcn_mfma_f32_16x16x32_f16(wa, vb[n], hacc[sub][m][n], 0, 0, 0);
        }
      }
      __builtin_amdgcn_s_setprio(0);
      vb[0] = vbn[0]; vb[1] = vbn[1];
    }
    __syncthreads();   // Ws reads done before next pass overwrites
  }
  #pragma unroll
  for (int sub = 0; sub < 2; ++sub)
    #pragma unroll
    for (int m = 0; m < 2; ++m)
      #pragma unroll
      for (int i = 0; i < 4; ++i) {
        float v = nacc[sub][m][i];
        v += __shfl_xor(v, 1); v += __shfl_xor(v, 2);
        v += __shfl_xor(v, 4); v += __shfl_xor(v, 8);
        if (lrow == 0) nsh[sub][wid][m * 16 + kseg * 4 + i] = v;
      }
  __syncthreads();
  if (tid < 64) {
    const int sub = tid >> 5, sr = tid & 31;
    float tot = 0.0f;
    #pragma unroll
    for (int w = 0; w < 8; ++w) tot += nsh[sub][w][sr];
    const float vm = vMArr[(long)bh * S_LEN + r0[sub] + sr];
    const float vecN = fmaxf(fabsf(tot), expf(-vm));
    invs[sub][sr] = 1.0f / (vecN + 1e-6f);
  }
  __syncthreads();
  #pragma unroll
  for (int sub = 0; sub < 2; ++sub)
    #pragma unroll
    for (int m = 0; m < 2; ++m)
      #pragma unroll
      for (int i = 0; i < 4; ++i) {
        const int row = m * 16 + kseg * 4 + i;
        const float inv = invs[sub][row];
        hacc[sub][m][0][i] *= inv;
        hacc[sub][m][1][i] *= inv;
        float s1 = hacc[sub][m][0][i] + hacc[sub][m][1][i];
        float s2 = hacc[sub][m][0][i] * hacc[sub][m][0][i]
                 + hacc[sub][m][1][i] * hacc[sub][m][1][i];
        s1 += __shfl_xor(s1, 1); s2 += __shfl_xor(s2, 1);
        s1 += __shfl_xor(s1, 2); s2 += __shfl_xor(s2, 2);
        s1 += __shfl_xor(s1, 4); s2 += __shfl_xor(s2, 4);
        s1 += __shfl_xor(s1, 8); s2 += __shfl_xor(s2, 8);
        if (lrow == 0) { nsh[sub][wid][row] = s1; s2sh[sub][wid][row] = s2; }
      }
  __syncthreads();
  if (tid < 64) {
    const int sub = tid >> 5, sr = tid & 31;
    float s1 = 0.0f, s2 = 0.0f;
    #pragma unroll
    for (int w = 0; w < 8; ++w) { s1 += nsh[sub][w][sr]; s2 += s2sh[sub][w][sr]; }
    const float mu = s1 * (1.0f / 256.0f);
    const float var = s2 * (1.0f / 256.0f) - mu * mu;
    musl[sub][sr] = mu;
    rssl[sub][sr] = rsqrtf(var + 1e-6f);
  }
  __syncthreads();
  #pragma unroll
  for (int sub = 0; sub < 2; ++sub)
    #pragma unroll
    for (int m = 0; m < 2; ++m)
      #pragma unroll
      for (int n = 0; n < 2; ++n)
        #pragma unroll
        for (int i = 0; i < 4; ++i) {
          const int row = m * 16 + kseg * 4 + i;
          const int d = dbase + n * 16 + lrow;
          const long gr = r0[sub] + row;
          const float hn = (hacc[sub][m][n][i] - musl[sub][row]) * rssl[sub][row] * gam[d];
          const float o = (float)Og[((long)gr) * NQKVO + d];
          ub[(long)(b * S_LEN + gr) * EMB + h * DH_ + d] =
              f2h(hn * (1.0f / (1.0f + expf(-o))));
        }
}

// ---------------------------------------------------------------------------
extern "C" void kernel_launch(void* const* d_in, const int* in_sizes, int n_in,
                              void* d_out, int out_size, void* d_ws, size_t ws_size,
                              hipStream_t stream)
{
  (void)in_sizes; (void)n_in; (void)out_size; (void)ws_size;
  const float* x     = (const float*)d_in[0];
  const float* Wq    = (const float*)d_in[1];
  const float* Wk    = (const float*)d_in[2];
  const float* Wv    = (const float*)d_in[3];
  const float* Wog   = (const float*)d_in[4];
  const float* Wi    = (const float*)d_in[5];
  const float* bi    = (const float*)d_in[6];
  const float* Wf    = (const float*)d_in[7];
  const float* bfg   = (const float*)d_in[8];
  const float* gamma = (const float*)d_in[9];
  const float* Wout  = (const float*)d_in[10];

  char* base = (char*)d_ws;
  size_t off = 0;
  auto take = [&](size_t bytes) -> char* {
    char* p = base + off;
    off += (bytes + 255) & ~(size_t)255;
    return p;
  };
  _Float16* xh    = (_Float16*)take((size_t)TOKENS * EMB * 2);        //  8 MB
  _Float16* WcatT = (_Float16*)take((size_t)NQKVO * EMB * 2);         // 19.4 MB
  _Float16* WoutT = (_Float16*)take((size_t)EMB * EMB * 2);           //  8 MB
  _Float16* qkvo  = (_Float16*)take((size_t)TOKENS * NQKVO * 2);      // 19.4 MB
  _Float16* vt    = (_Float16*)take((size_t)2 * DH_ * S_LEN * 2);     //  1 MB
  _Float16* ub    = (_Float16*)take((size_t)TOKENS * EMB * 2);        //  8 MB
  float*    aA    = (float*)take((size_t)NBH * S_LEN * 4);
  float*    mA    = (float*)take((size_t)NBH * S_LEN * 4);
  float*    vM    = (float*)take((size_t)NBH * S_LEN * 4);
  float*    y     = (float*)d_out;

  const dim3 blk(256);
  // --- merged prep: x cast + all weight transposes + i/f rows (1 launch) ---
  prep_kernel<<<dim3(TOKENS + 3328 + 64), blk, 0, stream>>>(
      x, Wq, Wk, Wv, Wog, Wout, Wi, Wf, xh, WcatT, WoutT);
  // --- fused QKVO+if projection: [2048,4736] = xh @ WcatT^T (16m x 37n) ---
  gemm_bt_kernel<_Float16, 128><<<dim3(16 * 37), blk, 0, stream>>>(
      xh, WcatT, qkvo, EMB, EMB, EMB, NQKVO, 16);
  // --- merged mid: gates (from qkvo z-cols) + V^T transpose ---
  mid_kernel<<<dim3(NBH + 128), blk, 0, stream>>>(qkvo, vt, bi, bfg, aA, mA, vM);
  // --- fused mLSTM backend + LN + output gate (writes ub directly) ---
  att_fused_kernel<<<dim3(16, NBH), dim3(512), 0, stream>>>(
      qkvo, vt, aA, mA, vM, gamma, ub);
  // --- output projection: BM=64/BK=64 2-buf, 512 blocks (R18) ---
  gemm_out_kernel<<<dim3(32 * 16), blk, 0, stream>>>(
      ub, WoutT, y, EMB, EMB, EMB, EMB, 32);
}

// Round 21
// 157.677 us; speedup vs baseline: 1.0813x; 1.0113x over previous
//
#include <hip/hip_runtime.h>
#include <math.h>

#define S_LEN  1024
#define EMB    2048
#define NH_    8
#define DH_    256
#define TOKENS 2048   // B*S
#define NBH    16     // B*NH
#define NQKVO  4736   // 2048 q | 256 k | 256 v | 2048 o | 8 i | 8 f | 112 pad

#define LOG2E  1.4426950408889634f
#define LN16   2.772588722239781f

typedef __attribute__((ext_vector_type(4))) float    f32x4;
typedef __attribute__((ext_vector_type(8))) _Float16 f16x8;
typedef __attribute__((ext_vector_type(4))) _Float16 f16x4;

__device__ __forceinline__ _Float16 f2h(float f) { return (_Float16)f; }

// async global->LDS, 16B per lane; LDS dest = wave-uniform base + lane*16
__device__ __forceinline__ void gload16(const void* g, void* l) {
  __builtin_amdgcn_global_load_lds(
      (const __attribute__((address_space(1))) void*)g,
      (__attribute__((address_space(3))) void*)l, 16, 0, 0);
}

// ---------------------------------------------------------------------------
// Merged prep (one launch): x cast | big W transposes | Wi/Wf rows + pad.
// ---------------------------------------------------------------------------
__global__ __launch_bounds__(256) void prep_kernel(
    const float* __restrict__ x,
    const float* __restrict__ Wq, const float* __restrict__ Wk,
    const float* __restrict__ Wv, const float* __restrict__ Wog,
    const float* __restrict__ Wout,
    const float* __restrict__ Wi, const float* __restrict__ Wf,
    _Float16* __restrict__ xh,
    _Float16* __restrict__ WcatT, _Float16* __restrict__ WoutT)
{
  __shared__ float shmem[64][65];
  int t = blockIdx.x;
  const int tid = threadIdx.x;
  if (t < TOKENS) {
    const long base = (long)t * EMB + tid * 8;
    const float4 a = *(const float4*)(x + base);
    const float4 b = *(const float4*)(x + base + 4);
    f16x8 o = {f2h(a.x), f2h(a.y), f2h(a.z), f2h(a.w),
               f2h(b.x), f2h(b.y), f2h(b.z), f2h(b.w)};
    *(f16x8*)(xh + base) = o;
  } else if (t < TOKENS + 3328) {
    t -= TOKENS;
    const float* in; _Float16* out; int ldi, ct;
    if (t < 1024)      { in = Wq;   out = WcatT;                    ldi = 2048; ct = 32; }
    else if (t < 1152) { t -= 1024; in = Wk;  out = WcatT + (long)2048 * EMB; ldi = 256; ct = 4; }
    else if (t < 1280) { t -= 1152; in = Wv;  out = WcatT + (long)2304 * EMB; ldi = 256; ct = 4; }
    else if (t < 2304) { t -= 1280; in = Wog; out = WcatT + (long)2560 * EMB; ldi = 2048; ct = 32; }
    else               { t -= 2304; in = Wout; out = WoutT;         ldi = 2048; ct = 32; }
    const long c0 = (long)(t % ct) * 64, r0 = (long)(t / ct) * 64;
    const int lx = tid & 63, ly = tid >> 6;
    #pragma unroll
    for (int i = 0; i < 16; ++i)
      shmem[ly + i * 4][lx] = in[(r0 + ly + i * 4) * ldi + c0 + lx];
    __syncthreads();
    #pragma unroll
    for (int i = 0; i < 16; ++i)
      out[(c0 + ly + i * 4) * EMB + r0 + lx] = f2h(shmem[lx][ly + i * 4]);
  } else {
    const int j = t - (TOKENS + 3328);           // 0..63, 2 rows each
    const int row = 4608 + j * 2 + (tid >> 7);
    const int c0 = (tid & 127) * 16;
    _Float16* dst = WcatT + (long)row * EMB + c0;
    if (row < 4616) {
      const int jj = row - 4608;
      #pragma unroll
      for (int k = 0; k < 16; ++k) dst[k] = f2h(Wi[(long)(c0 + k) * 8 + jj]);
    } else if (row < 4624) {
      const int jj = row - 4616;
      #pragma unroll
      for (int k = 0; k < 16; ++k) dst[k] = f2h(Wf[(long)(c0 + k) * 8 + jj]);
    } else {
      #pragma unroll
      for (int k = 0; k < 16; ++k) dst[k] = (_Float16)0.0f;
    }
  }
}

// ---------------------------------------------------------------------------
// f16 GEMM, BMx128 tile, BK=32, 4 waves, 3-deep prefetch (R12-proven loop).
// Used for the QKVO+if projection.
// ---------------------------------------------------------------------------
template<typename CT, int BM>
__global__ __launch_bounds__(256) void gemm_bt_kernel(
    const _Float16* __restrict__ Ag, const _Float16* __restrict__ Btg,
    CT* __restrict__ Cg, int K, int lda, int ldb, int ldc, int mtiles)
{
  constexpr int MR = BM / 32;
  __shared__ _Float16 As[3][BM * 32];
  __shared__ _Float16 Bs[3][128 * 32];
  const int tid = threadIdx.x;
  const int lane = tid & 63, wid = tid >> 6;
  const int cpx = gridDim.x >> 3;
  const int wg = ((int)blockIdx.x & 7) * cpx + ((int)blockIdx.x >> 3);
  const int m0 = (wg % mtiles) * BM;
  const int n0 = (wg / mtiles) * 128;
  const _Float16* Ap = Ag + (long)m0 * lda;
  const _Float16* Bp = Btg + (long)n0 * ldb;
  const int wr = wid >> 1, wc = wid & 1;
  const int lrow = lane & 15, kseg = lane >> 4;

  auto stage = [&](int b, int k0) {
    #pragma unroll
    for (int i = 0; i < BM / 64; ++i) {
      const int cbase = (i * 4 + wid) * 64;
      const int row = (cbase >> 2) + (lane >> 2);
      const int src = ((lane & 3) ^ ((row >> 1) & 3)) * 8;
      gload16(Ap + (long)row * lda + k0 + src, (char*)As[b] + cbase * 16);
    }
    #pragma unroll
    for (int i = 0; i < 2; ++i) {
      const int cbase = (i * 4 + wid) * 64;
      const int row = (cbase >> 2) + (lane >> 2);
      const int src = ((lane & 3) ^ ((row >> 1) & 3)) * 8;
      gload16(Bp + (long)row * ldb + k0 + src, (char*)Bs[b] + cbase * 16);
    }
  };

  const int nt = K >> 5;
  f32x4 acc[MR][4] = {};
  stage(0, 0);
  if (nt > 1) stage(1, 32);
  for (int t = 0; t < nt; ++t) {
    if (t + 2 < nt) {
      stage((t + 2) % 3, (t + 2) * 32);
      if constexpr (BM == 128) asm volatile("s_waitcnt vmcnt(8)" ::: "memory");
      else                     asm volatile("s_waitcnt vmcnt(6)" ::: "memory");
    } else if (t + 1 < nt) {
      if constexpr (BM == 128) asm volatile("s_waitcnt vmcnt(4)" ::: "memory");
      else                     asm volatile("s_waitcnt vmcnt(3)" ::: "memory");
    } else {
      asm volatile("s_waitcnt vmcnt(0)" ::: "memory");
    }
    __builtin_amdgcn_s_barrier();
    __builtin_amdgcn_sched_barrier(0);
    const int buf = t % 3;
    f16x8 fa[MR], fb[4];
    #pragma unroll
    for (int m = 0; m < MR; ++m) {
      const int row = wr * (BM / 2) + m * 16 + lrow;
      fa[m] = *(const f16x8*)&As[buf][row * 32 + ((kseg ^ ((row >> 1) & 3)) << 3)];
    }
    #pragma unroll
    for (int n = 0; n < 4; ++n) {
      const int row = wc * 64 + n * 16 + lrow;
      fb[n] = *(const f16x8*)&Bs[buf][row * 32 + ((kseg ^ ((row >> 1) & 3)) << 3)];
    }
    #pragma unroll
    for (int m = 0; m < MR; ++m)
      #pragma unroll
      for (int n = 0; n < 4; ++n)
        acc[m][n] = __builtin_amdgcn_mfma_f32_16x16x32_f16(fa[m], fb[n], acc[m][n], 0, 0, 0);
    __builtin_amdgcn_s_barrier();
  }
  #pragma unroll
  for (int m = 0; m < MR; ++m)
    #pragma unroll
    for (int n = 0; n < 4; ++n)
      #pragma unroll
      for (int i = 0; i < 4; ++i) {
        const int r = m0 + wr * (BM / 2) + m * 16 + kseg * 4 + i;  // row=(lane>>4)*4+i (m89)
        const int c = n0 + wc * 64 + n * 16 + lrow;                // col=lane&15
        Cg[(long)r * ldc + c] = (CT)acc[m][n][i];
      }
}

// ---------------------------------------------------------------------------
// Output projection GEMM (R18): 64x128 tile, BK=64, 2-buffer, 4 waves.
// ---------------------------------------------------------------------------
__global__ __launch_bounds__(256) void gemm_out_kernel(
    const _Float16* __restrict__ Ag, const _Float16* __restrict__ Btg,
    float* __restrict__ Cg, int K, int lda, int ldb, int ldc, int mtiles)
{
  __shared__ _Float16 As[2][64 * 64];
  __shared__ _Float16 Bs[2][128 * 64];
  const int tid = threadIdx.x;
  const int lane = tid & 63, wid = tid >> 6;
  const int cpx = gridDim.x >> 3;
  const int wg = ((int)blockIdx.x & 7) * cpx + ((int)blockIdx.x >> 3);
  const int m0 = (wg % mtiles) * 64;
  const int n0 = (wg / mtiles) * 128;
  const _Float16* Ap = Ag + (long)m0 * lda;
  const _Float16* Bp = Btg + (long)n0 * ldb;
  const int wr = wid >> 1, wc = wid & 1;
  const int lrow = lane & 15, kseg = lane >> 4;

  auto stage = [&](int b, int k0) {
    #pragma unroll
    for (int i = 0; i < 2; ++i) {                 // A: 512 chunks (8/row)
      const int cbase = (i * 4 + wid) * 64;
      const int c = cbase + lane;
      const int row = c >> 3, slot = c & 7;
      gload16(Ap + (long)row * lda + k0 + (slot ^ (row & 7)) * 8,
              (char*)As[b] + cbase * 16);
    }
    #pragma unroll
    for (int i = 0; i < 4; ++i) {                 // B: 1024 chunks (8/row)
      const int cbase = (i * 4 + wid) * 64;
      const int c = cbase + lane;
      const int row = c >> 3, slot = c & 7;
      gload16(Bp + (long)row * ldb + k0 + (slot ^ (row & 7)) * 8,
              (char*)Bs[b] + cbase * 16);
    }
  };

  const int nt = K >> 6;                          // K-tiles of 64
  f32x4 acc[2][4] = {};
  stage(0, 0);
  int buf = 0;
  for (int t = 0; t < nt; ++t) {
    if (t + 1 < nt) {
      stage(buf ^ 1, (t + 1) * 64);               // prefetch next tile
      asm volatile("s_waitcnt vmcnt(6)" ::: "memory");  // t's 6 loads done
    } else {
      asm volatile("s_waitcnt vmcnt(0)" ::: "memory");
    }
    __builtin_amdgcn_s_barrier();
    __builtin_amdgcn_sched_barrier(0);
    #pragma unroll
    for (int kk = 0; kk < 2; ++kk) {              // two K=32 sub-steps
      f16x8 fa[2], fb[4];
      #pragma unroll
      for (int m = 0; m < 2; ++m) {
        const int row = wr * 32 + m * 16 + lrow;
        fa[m] = *(const f16x8*)&As[buf][row * 64 + (((kk * 4 + kseg) ^ (row & 7)) << 3)];
      }
      #pragma unroll
      for (int n = 0; n < 4; ++n) {
        const int row = wc * 64 + n * 16 + lrow;
        fb[n] = *(const f16x8*)&Bs[buf][row * 64 + (((kk * 4 + kseg) ^ (row & 7)) << 3)];
      }
      #pragma unroll
      for (int m = 0; m < 2; ++m)
        #pragma unroll
        for (int n = 0; n < 4; ++n)
          acc[m][n] = __builtin_amdgcn_mfma_f32_16x16x32_f16(fa[m], fb[n], acc[m][n], 0, 0, 0);
    }
    __builtin_amdgcn_s_barrier();
    buf ^= 1;
  }
  #pragma unroll
  for (int m = 0; m < 2; ++m)
    #pragma unroll
    for (int n = 0; n < 4; ++n)
      #pragma unroll
      for (int i = 0; i < 4; ++i) {
        const int r = m0 + wr * 32 + m * 16 + kseg * 4 + i;
        const int c = n0 + wc * 64 + n * 16 + lrow;
        Cg[(long)r * ldc + c] = acc[m][n][i];
      }
}

// ---------------------------------------------------------------------------
// Merged mid stage (one launch): gates (wave-scan, z from qkvo) + V^T.
// R21: gate arrays pre-scaled for exp2-based attention —
//   aA2 = (a - ln16)*log2e, mA2 = m*log2e, vM2 = (cf+m)*log2e.
// att then computes w = qk * exp2(aA2 - mA2)  (== qk/16 * exp(a-m), exact)
// and vecN uses exp2(-vM2) == exp(-vecM).
// ---------------------------------------------------------------------------
__global__ __launch_bounds__(256) void mid_kernel(
    const _Float16* __restrict__ qkvo, _Float16* __restrict__ vt,
    const float* __restrict__ bi, const float* __restrict__ bfg,
    float* __restrict__ aArr, float* __restrict__ mArr, float* __restrict__ vMArr)
{
  __shared__ float shmem[64][65];
  const int tid = threadIdx.x;
  int t = blockIdx.x;
  if (t < NBH) {
    const int bh = t;
    const int b = bh >> 3, h = bh & 7;
    const int lane = tid & 63, wid = tid >> 6;
    float* wsum = &shmem[0][0];
    float* wmax = &shmem[1][0];
    const float bih = bi[h], bfh = bfg[h];
    const int s4 = tid * 4;
    const _Float16* zb = qkvo + (long)(b * S_LEN + s4) * NQKVO;
    float zf[4], zi[4];
    #pragma unroll
    for (int k = 0; k < 4; ++k) {
      zi[k] = 15.0f * tanhf(((float)zb[(long)k * NQKVO + 4608 + h] + bih) * (1.0f / 15.0f));
      zf[k] = 15.0f * tanhf(((float)zb[(long)k * NQKVO + 4616 + h] + bfh) * (1.0f / 15.0f));
    }
    float lg[4];
    #pragma unroll
    for (int k = 0; k < 4; ++k)
      lg[k] = fminf(zf[k], 0.0f) - log1pf(expf(-fabsf(zf[k])));
    float c0 = lg[0], c1 = c0 + lg[1], c2 = c1 + lg[2], c3 = c2 + lg[3];
    float ts = c3;
    #pragma unroll
    for (int off = 1; off < 64; off <<= 1) {
      const float o = __shfl_up(ts, off);
      if (lane >= off) ts += o;
    }
    const float texcl = ts - c3;
    if (lane == 63) wsum[wid] = ts;
    __syncthreads();
    float woff = 0.0f;
    for (int w = 0; w < wid; ++w) woff += wsum[w];
    const float base = woff + texcl;
    const float cf[4] = { base + c0, base + c1, base + c2, base + c3 };
    const float a[4] = { zi[0] - cf[0], zi[1] - cf[1], zi[2] - cf[2], zi[3] - cf[3] };
    float l1 = fmaxf(a[0], a[1]), l3 = fmaxf(fmaxf(l1, a[2]), a[3]);
    float incl = l3;
    #pragma unroll
    for (int off = 1; off < 64; off <<= 1) {
      const float o = __shfl_up(incl, off);
      if (lane >= off) incl = fmaxf(incl, o);
    }
    float excl = __shfl_up(incl, 1);
    if (lane == 0) excl = -3.0e38f;
    if (lane == 63) wmax[wid] = incl;
    __syncthreads();
    float wpre = -3.0e38f;
    for (int w = 0; w < wid; ++w) wpre = fmaxf(wpre, wmax[w]);
    const float pre = fmaxf(wpre, excl);
    float mm[4];
    mm[0] = fmaxf(pre, a[0]); mm[1] = fmaxf(mm[0], a[1]);
    mm[2] = fmaxf(mm[1], a[2]); mm[3] = fmaxf(mm[2], a[3]);
    float4 av = { (a[0] - LN16) * LOG2E, (a[1] - LN16) * LOG2E,
                  (a[2] - LN16) * LOG2E, (a[3] - LN16) * LOG2E };
    float4 mv = { mm[0] * LOG2E, mm[1] * LOG2E, mm[2] * LOG2E, mm[3] * LOG2E };
    float4 vv = { (cf[0] + mm[0]) * LOG2E, (cf[1] + mm[1]) * LOG2E,
                  (cf[2] + mm[2]) * LOG2E, (cf[3] + mm[3]) * LOG2E };
    *(float4*)(aArr + (long)bh * S_LEN + s4) = av;
    *(float4*)(mArr + (long)bh * S_LEN + s4) = mv;
    *(float4*)(vMArr + (long)bh * S_LEN + s4) = vv;
  } else {
    t -= NBH;
    const int z = t >> 6, rem = t & 63;
    const long c0 = (long)(rem & 3) * 64;    // d-tile
    const long r0 = (long)(rem >> 2) * 64;   // s-tile
    const _Float16* ipt = qkvo + (long)z * S_LEN * NQKVO + 2304;
    _Float16* op = vt + (long)z * DH_ * S_LEN;
    const int lx = tid & 63, ly = tid >> 6;
    #pragma unroll
    for (int i = 0; i < 16; ++i)
      shmem[ly + i * 4][lx] = (float)ipt[(r0 + ly + i * 4) * NQKVO + c0 + lx];
    __syncthreads();
    #pragma unroll
    for (int i = 0; i < 16; ++i)
      op[(c0 + ly + i * 4) * S_LEN + r0 + lx] = f2h(shmem[lx][ly + i * 4]);
  }
}

// ---------------------------------------------------------------------------
// Fused mLSTM attention + LN + output gate, triangle-paired, QBLK=32,
// 512 threads / 8 waves.  R21: exp2-based weighting (gate arrays pre-scaled
// in mid), 1/16 folded into aA2, wave-uniform full-tile fast path skipping
// the per-element causal compare on interior passes.
// ---------------------------------------------------------------------------
__global__ __launch_bounds__(512) void att_fused_kernel(
    const _Float16* __restrict__ qkvo, const _Float16* __restrict__ vt,
    const float* __restrict__ aArr, const float* __restrict__ mArr,
    const float* __restrict__ vMArr, const float* __restrict__ gamma,
    _Float16* __restrict__ ub)
{
  __shared__ _Float16 Qs[2][32 * 256];   // swizzled: 32 chunks/row, ^(row&7)
  __shared__ _Float16 Ws[2][32 * 128];   // swizzled: 16 chunks/row, ^((row&7)<<1)
  __shared__ float nsh[2][8][32];
  __shared__ float s2sh[2][8][32];
  __shared__ float invs[2][32];
  __shared__ float musl[2][32], rssl[2][32];
  const int tid = threadIdx.x;
  const int lane = tid & 63, wid = tid >> 6;     // 8 waves
  const int bh = blockIdx.y;
  const int b = bh >> 3, h = bh & 7;
  const int r0[2] = { (int)blockIdx.x * 32, (31 - (int)blockIdx.x) * 32 };
  const _Float16* Qg = qkvo + (long)(b * S_LEN) * NQKVO + h * DH_;
  const _Float16* Kg = qkvo + (long)(b * S_LEN) * NQKVO + 2048;
  const _Float16* Og = qkvo + (long)(b * S_LEN) * NQKVO + 2560 + h * DH_;
  const _Float16* Vt = vt + (long)b * DH_ * S_LEN;
  const float* aA = aArr + (long)bh * S_LEN;
  const float* mA = mArr + (long)bh * S_LEN;
  const float* gam = gamma + h * DH_;
  const int lrow = lane & 15, kseg = lane >> 4;
  const int tbase = 16 * wid;                    // QK t-slice per wave
  const int dbase = 32 * wid;                    // PV d-slice per wave

  #pragma unroll
  for (int i = 0; i < 4; ++i) {
    const int cbase = (i * 8 + wid) * 64;        // wave-uniform
    const int c = cbase + lane;
    const int sub = c >> 10, row = (c >> 5) & 31, slot = c & 31;
    gload16(Qg + (long)(r0[sub] + row) * NQKVO + (slot ^ (row & 7)) * 8,
            (char*)Qs + cbase * 16);
  }

  float m_s[2][2][4];
  #pragma unroll
  for (int sub = 0; sub < 2; ++sub)
    #pragma unroll
    for (int m = 0; m < 2; ++m)
      #pragma unroll
      for (int i = 0; i < 4; ++i)
        m_s[sub][m][i] = mA[r0[sub] + m * 16 + kseg * 4 + i];
  __syncthreads();   // Q staged (drains vmcnt)

  f32x4 hacc[2][2][2] = {};
  float nacc[2][2][4] = {};
  for (int n0 = 0; n0 <= r0[1]; n0 += 128) {
    f32x4 acc[2][2] = {};
    f16x8 fb, fbn;
    fb = *(const f16x8*)(Kg + (long)(n0 + tbase + lrow) * NQKVO + kseg * 8);
    #pragma unroll
    for (int k0 = 0; k0 < DH_; k0 += 32) {
      if (k0 + 32 < DH_)
        fbn = *(const f16x8*)(Kg + (long)(n0 + tbase + lrow) * NQKVO + k0 + 32 + kseg * 8);
      const int chunk = (k0 >> 3) + kseg;
      __builtin_amdgcn_s_setprio(1);
      #pragma unroll
      for (int sub = 0; sub < 2; ++sub) {
        if (n0 > r0[sub]) continue;
        #pragma unroll
        for (int m = 0; m < 2; ++m) {
          const int qrow = m * 16 + lrow;
          const f16x8 fa = *(const f16x8*)&Qs[sub][qrow * 256 + ((chunk ^ (qrow & 7)) << 3)];
          acc[sub][m] = __builtin_amdgcn_mfma_f32_16x16x32_f16(fa, fb, acc[sub][m], 0, 0, 0);
        }
      }
      __builtin_amdgcn_s_setprio(0);
      fb = fbn;
    }
    // ---- weighting -> Ws (swizzled), exp2 + fast full-tile path ----
    const float a_t = aA[n0 + tbase + lrow];
    const int t = tbase + lrow;                   // local col 0..127 (const/thread)
    #pragma unroll
    for (int sub = 0; sub < 2; ++sub) {
      if (n0 > r0[sub]) continue;
      if (n0 + 127 <= r0[sub]) {                  // full tile: no causal check
        #pragma unroll
        for (int m = 0; m < 2; ++m)
          #pragma unroll
          for (int i = 0; i < 4; ++i) {
            const int sr = m * 16 + kseg * 4 + i;
            const float w = acc[sub][m][i] * exp2f(a_t - m_s[sub][m][i]);
            nacc[sub][m][i] += w;
            Ws[sub][sr * 128 + (((t >> 3) ^ ((sr & 7) << 1)) << 3) + (t & 7)] = f2h(w);
          }
      } else {
        #pragma unroll
        for (int m = 0; m < 2; ++m)
          #pragma unroll
          for (int i = 0; i < 4; ++i) {
            const int sr = m * 16 + kseg * 4 + i;
            float w = 0.0f;
            if (n0 + t <= r0[sub] + sr)
              w = acc[sub][m][i] * exp2f(a_t - m_s[sub][m][i]);
            nacc[sub][m][i] += w;
            Ws[sub][sr * 128 + (((t >> 3) ^ ((sr & 7) << 1)) << 3) + (t & 7)] = f2h(w);
          }
      }
    }
    f16x8 vb[2], vbn[2];
    #pragma unroll
    for (int n = 0; n < 2; ++n)
      vb[n] = *(const f16x8*)(Vt + (long)(dbase + n * 16 + lrow) * S_LEN + n0 + kseg * 8);
    __syncthreads();
    #pragma unroll
    for (int kt = 0; kt < 128; kt += 32) {
      if (kt + 32 < 128) {
        #pragma unroll
        for (int n = 0; n < 2; ++n)
          vbn[n] = *(const f16x8*)(Vt + (long)(dbase + n * 16 + lrow) * S_LEN + n0 + kt + 32 + kseg * 8);
      }
      const int chunk = (kt >> 3) + kseg;
      __builtin_amdgcn_s_setprio(1);
      #pragma unroll
      for (int sub = 0; sub < 2; ++sub) {
        if (n0 > r0[sub]) continue;
        #pragma unroll
        for (int m = 0; m < 2; ++m) {
          const int row = m * 16 + lrow;
          const f16x8 wa = *(const f16x8*)&Ws[sub][row * 128 + ((chunk ^ ((row & 7) << 1)) << 3)];
          #pragma unroll
          for (int n = 0; n < 2; ++n)
            hacc[sub][m][n] = __builtin_amdgcn_mfma_f32_16x16x32_f16(wa, vb[n], hacc[sub][m][n], 0, 0, 0);
        }
      }
      __builtin_amdgcn_s_setprio(0);
      vb[0] = vbn[0]; vb[1] = vbn[1];
    }
    __syncthreads();   // Ws reads done before next pass overwrites
  }
  #pragma unroll
  for (int sub = 0; sub < 2; ++sub)
    #pragma unroll
    for (int m = 0; m < 2; ++m)
      #pragma unroll
      for (int i = 0; i < 4; ++i) {
        float v = nacc[sub][m][i];
        v += __shfl_xor(v, 1); v += __shfl_xor(v, 2);
        v += __shfl_xor(v, 4); v += __shfl_xor(v, 8);
        if (lrow == 0) nsh[sub][wid][m * 16 + kseg * 4 + i] = v;
      }
  __syncthreads();
  if (tid < 64) {
    const int sub = tid >> 5, sr = tid & 31;
    float tot = 0.0f;
    #pragma unroll
    for (int w = 0; w < 8; ++w) tot += nsh[sub][w][sr];
    const float vm = vMArr[(long)bh * S_LEN + r0[sub] + sr];   // pre-scaled by log2e
    const float vecN = fmaxf(fabsf(tot), exp2f(-vm));
    invs[sub][sr] = 1.0f / (vecN + 1e-6f);
  }
  __syncthreads();
  #pragma unroll
  for (int sub = 0; sub < 2; ++sub)
    #pragma unroll
    for (int m = 0; m < 2; ++m)
      #pragma unroll
      for (int i = 0; i < 4; ++i) {
        const int row = m * 16 + kseg * 4 + i;
        const float inv = invs[sub][row];
        hacc[sub][m][0][i] *= inv;
        hacc[sub][m][1][i] *= inv;
        float s1 = hacc[sub][m][0][i] + hacc[sub][m][1][i];
        float s2 = hacc[sub][m][0][i] * hacc[sub][m][0][i]
                 + hacc[sub][m][1][i] * hacc[sub][m][1][i];
        s1 += __shfl_xor(s1, 1); s2 += __shfl_xor(s2, 1);
        s1 += __shfl_xor(s1, 2); s2 += __shfl_xor(s2, 2);
        s1 += __shfl_xor(s1, 4); s2 += __shfl_xor(s2, 4);
        s1 += __shfl_xor(s1, 8); s2 += __shfl_xor(s2, 8);
        if (lrow == 0) { nsh[sub][wid][row] = s1; s2sh[sub][wid][row] = s2; }
      }
  __syncthreads();
  if (tid < 64) {
    const int sub = tid >> 5, sr = tid & 31;
    float s1 = 0.0f, s2 = 0.0f;
    #pragma unroll
    for (int w = 0; w < 8; ++w) { s1 += nsh[sub][w][sr]; s2 += s2sh[sub][w][sr]; }
    const float mu = s1 * (1.0f / 256.0f);
    const float var = s2 * (1.0f / 256.0f) - mu * mu;
    musl[sub][sr] = mu;
    rssl[sub][sr] = rsqrtf(var + 1e-6f);
  }
  __syncthreads();
  #pragma unroll
  for (int sub = 0; sub < 2; ++sub)
    #pragma unroll
    for (int m = 0; m < 2; ++m)
      #pragma unroll
      for (int n = 0; n < 2; ++n)
        #pragma unroll
        for (int i = 0; i < 4; ++i) {
          const int row = m * 16 + kseg * 4 + i;
          const int d = dbase + n * 16 + lrow;
          const long gr = r0[sub] + row;
          const float hn = (hacc[sub][m][n][i] - musl[sub][row]) * rssl[sub][row] * gam[d];
          const float o = (float)Og[((long)gr) * NQKVO + d];
          ub[(long)(b * S_LEN + gr) * EMB + h * DH_ + d] =
              f2h(hn * (1.0f / (1.0f + expf(-o))));
        }
}

// ---------------------------------------------------------------------------
extern "C" void kernel_launch(void* const* d_in, const int* in_sizes, int n_in,
                              void* d_out, int out_size, void* d_ws, size_t ws_size,
                              hipStream_t stream)
{
  (void)in_sizes; (void)n_in; (void)out_size; (void)ws_size;
  const float* x     = (const float*)d_in[0];
  const float* Wq    = (const float*)d_in[1];
  const float* Wk    = (const float*)d_in[2];
  const float* Wv    = (const float*)d_in[3];
  const float* Wog   = (const float*)d_in[4];
  const float* Wi    = (const float*)d_in[5];
  const float* bi    = (const float*)d_in[6];
  const float* Wf    = (const float*)d_in[7];
  const float* bfg   = (const float*)d_in[8];
  const float* gamma = (const float*)d_in[9];
  const float* Wout  = (const float*)d_in[10];

  char* base = (char*)d_ws;
  size_t off = 0;
  auto take = [&](size_t bytes) -> char* {
    char* p = base + off;
    off += (bytes + 255) & ~(size_t)255;
    return p;
  };
  _Float16* xh    = (_Float16*)take((size_t)TOKENS * EMB * 2);        //  8 MB
  _Float16* WcatT = (_Float16*)take((size_t)NQKVO * EMB * 2);         // 19.4 MB
  _Float16* WoutT = (_Float16*)take((size_t)EMB * EMB * 2);           //  8 MB
  _Float16* qkvo  = (_Float16*)take((size_t)TOKENS * NQKVO * 2);      // 19.4 MB
  _Float16* vt    = (_Float16*)take((size_t)2 * DH_ * S_LEN * 2);     //  1 MB
  _Float16* ub    = (_Float16*)take((size_t)TOKENS * EMB * 2);        //  8 MB
  float*    aA    = (float*)take((size_t)NBH * S_LEN * 4);
  float*    mA    = (float*)take((size_t)NBH * S_LEN * 4);
  float*    vM    = (float*)take((size_t)NBH * S_LEN * 4);
  float*    y     = (float*)d_out;

  const dim3 blk(256);
  // --- merged prep: x cast + all weight transposes + i/f rows (1 launch) ---
  prep_kernel<<<dim3(TOKENS + 3328 + 64), blk, 0, stream>>>(
      x, Wq, Wk, Wv, Wog, Wout, Wi, Wf, xh, WcatT, WoutT);
  // --- fused QKVO+if projection: [2048,4736] = xh @ WcatT^T (16m x 37n) ---
  gemm_bt_kernel<_Float16, 128><<<dim3(16 * 37), blk, 0, stream>>>(
      xh, WcatT, qkvo, EMB, EMB, EMB, NQKVO, 16);
  // --- merged mid: gates (from qkvo z-cols, pre-scaled for exp2) + V^T ---
  mid_kernel<<<dim3(NBH + 128), blk, 0, stream>>>(qkvo, vt, bi, bfg, aA, mA, vM);
  // --- fused mLSTM backend + LN + output gate (writes ub directly) ---
  att_fused_kernel<<<dim3(16, NBH), dim3(512), 0, stream>>>(
      qkvo, vt, aA, mA, vM, gamma, ub);
  // --- output projection: BM=64/BK=64 2-buf, 512 blocks (R18) ---
  gemm_out_kernel<<<dim3(32 * 16), blk, 0, stream>>>(
      ub, WoutT, y, EMB, EMB, EMB, EMB, 32);
}

// Round 22
// 157.284 us; speedup vs baseline: 1.0840x; 1.0025x over previous
//
#include <hip/hip_runtime.h>
#include <math.h>

#define S_LEN  1024
#define EMB    2048
#define NH_    8
#define DH_    256
#define TOKENS 2048   // B*S
#define NBH    16     // B*NH
#define NQKVO  4736   // 2048 q | 256 k | 256 v | 2048 o | 8 i | 8 f | 112 pad

#define LOG2E  1.4426950408889634f
#define LN16   2.772588722239781f

typedef __attribute__((ext_vector_type(4))) float    f32x4;
typedef __attribute__((ext_vector_type(8))) _Float16 f16x8;
typedef __attribute__((ext_vector_type(4))) _Float16 f16x4;

__device__ __forceinline__ _Float16 f2h(float f) { return (_Float16)f; }

// async global->LDS, 16B per lane; LDS dest = wave-uniform base + lane*16
__device__ __forceinline__ void gload16(const void* g, void* l) {
  __builtin_amdgcn_global_load_lds(
      (const __attribute__((address_space(1))) void*)g,
      (__attribute__((address_space(3))) void*)l, 16, 0, 0);
}

// ---------------------------------------------------------------------------
// Merged prep (one launch): x cast | big W transposes | Wi/Wf rows + pad.
// ---------------------------------------------------------------------------
__global__ __launch_bounds__(256) void prep_kernel(
    const float* __restrict__ x,
    const float* __restrict__ Wq, const float* __restrict__ Wk,
    const float* __restrict__ Wv, const float* __restrict__ Wog,
    const float* __restrict__ Wout,
    const float* __restrict__ Wi, const float* __restrict__ Wf,
    _Float16* __restrict__ xh,
    _Float16* __restrict__ WcatT, _Float16* __restrict__ WoutT)
{
  __shared__ float shmem[64][65];
  int t = blockIdx.x;
  const int tid = threadIdx.x;
  if (t < TOKENS) {
    const long base = (long)t * EMB + tid * 8;
    const float4 a = *(const float4*)(x + base);
    const float4 b = *(const float4*)(x + base + 4);
    f16x8 o = {f2h(a.x), f2h(a.y), f2h(a.z), f2h(a.w),
               f2h(b.x), f2h(b.y), f2h(b.z), f2h(b.w)};
    *(f16x8*)(xh + base) = o;
  } else if (t < TOKENS + 3328) {
    t -= TOKENS;
    const float* in; _Float16* out; int ldi, ct;
    if (t < 1024)      { in = Wq;   out = WcatT;                    ldi = 2048; ct = 32; }
    else if (t < 1152) { t -= 1024; in = Wk;  out = WcatT + (long)2048 * EMB; ldi = 256; ct = 4; }
    else if (t < 1280) { t -= 1152; in = Wv;  out = WcatT + (long)2304 * EMB; ldi = 256; ct = 4; }
    else if (t < 2304) { t -= 1280; in = Wog; out = WcatT + (long)2560 * EMB; ldi = 2048; ct = 32; }
    else               { t -= 2304; in = Wout; out = WoutT;         ldi = 2048; ct = 32; }
    const long c0 = (long)(t % ct) * 64, r0 = (long)(t / ct) * 64;
    const int lx = tid & 63, ly = tid >> 6;
    #pragma unroll
    for (int i = 0; i < 16; ++i)
      shmem[ly + i * 4][lx] = in[(r0 + ly + i * 4) * ldi + c0 + lx];
    __syncthreads();
    #pragma unroll
    for (int i = 0; i < 16; ++i)
      out[(c0 + ly + i * 4) * EMB + r0 + lx] = f2h(shmem[lx][ly + i * 4]);
  } else {
    const int j = t - (TOKENS + 3328);           // 0..63, 2 rows each
    const int row = 4608 + j * 2 + (tid >> 7);
    const int c0 = (tid & 127) * 16;
    _Float16* dst = WcatT + (long)row * EMB + c0;
    if (row < 4616) {
      const int jj = row - 4608;
      #pragma unroll
      for (int k = 0; k < 16; ++k) dst[k] = f2h(Wi[(long)(c0 + k) * 8 + jj]);
    } else if (row < 4624) {
      const int jj = row - 4616;
      #pragma unroll
      for (int k = 0; k < 16; ++k) dst[k] = f2h(Wf[(long)(c0 + k) * 8 + jj]);
    } else {
      #pragma unroll
      for (int k = 0; k < 16; ++k) dst[k] = (_Float16)0.0f;
    }
  }
}

// ---------------------------------------------------------------------------
// f16 GEMM, BMx128 tile, BK=32, 4 waves, 3-deep prefetch (R12-proven loop).
// Used for the QKVO+if projection.
// ---------------------------------------------------------------------------
template<typename CT, int BM>
__global__ __launch_bounds__(256) void gemm_bt_kernel(
    const _Float16* __restrict__ Ag, const _Float16* __restrict__ Btg,
    CT* __restrict__ Cg, int K, int lda, int ldb, int ldc, int mtiles)
{
  constexpr int MR = BM / 32;
  __shared__ _Float16 As[3][BM * 32];
  __shared__ _Float16 Bs[3][128 * 32];
  const int tid = threadIdx.x;
  const int lane = tid & 63, wid = tid >> 6;
  const int cpx = gridDim.x >> 3;
  const int wg = ((int)blockIdx.x & 7) * cpx + ((int)blockIdx.x >> 3);
  const int m0 = (wg % mtiles) * BM;
  const int n0 = (wg / mtiles) * 128;
  const _Float16* Ap = Ag + (long)m0 * lda;
  const _Float16* Bp = Btg + (long)n0 * ldb;
  const int wr = wid >> 1, wc = wid & 1;
  const int lrow = lane & 15, kseg = lane >> 4;

  auto stage = [&](int b, int k0) {
    #pragma unroll
    for (int i = 0; i < BM / 64; ++i) {
      const int cbase = (i * 4 + wid) * 64;
      const int row = (cbase >> 2) + (lane >> 2);
      const int src = ((lane & 3) ^ ((row >> 1) & 3)) * 8;
      gload16(Ap + (long)row * lda + k0 + src, (char*)As[b] + cbase * 16);
    }
    #pragma unroll
    for (int i = 0; i < 2; ++i) {
      const int cbase = (i * 4 + wid) * 64;
      const int row = (cbase >> 2) + (lane >> 2);
      const int src = ((lane & 3) ^ ((row >> 1) & 3)) * 8;
      gload16(Bp + (long)row * ldb + k0 + src, (char*)Bs[b] + cbase * 16);
    }
  };

  const int nt = K >> 5;
  f32x4 acc[MR][4] = {};
  stage(0, 0);
  if (nt > 1) stage(1, 32);
  for (int t = 0; t < nt; ++t) {
    if (t + 2 < nt) {
      stage((t + 2) % 3, (t + 2) * 32);
      if constexpr (BM == 128) asm volatile("s_waitcnt vmcnt(8)" ::: "memory");
      else                     asm volatile("s_waitcnt vmcnt(6)" ::: "memory");
    } else if (t + 1 < nt) {
      if constexpr (BM == 128) asm volatile("s_waitcnt vmcnt(4)" ::: "memory");
      else                     asm volatile("s_waitcnt vmcnt(3)" ::: "memory");
    } else {
      asm volatile("s_waitcnt vmcnt(0)" ::: "memory");
    }
    __builtin_amdgcn_s_barrier();
    __builtin_amdgcn_sched_barrier(0);
    const int buf = t % 3;
    f16x8 fa[MR], fb[4];
    #pragma unroll
    for (int m = 0; m < MR; ++m) {
      const int row = wr * (BM / 2) + m * 16 + lrow;
      fa[m] = *(const f16x8*)&As[buf][row * 32 + ((kseg ^ ((row >> 1) & 3)) << 3)];
    }
    #pragma unroll
    for (int n = 0; n < 4; ++n) {
      const int row = wc * 64 + n * 16 + lrow;
      fb[n] = *(const f16x8*)&Bs[buf][row * 32 + ((kseg ^ ((row >> 1) & 3)) << 3)];
    }
    #pragma unroll
    for (int m = 0; m < MR; ++m)
      #pragma unroll
      for (int n = 0; n < 4; ++n)
        acc[m][n] = __builtin_amdgcn_mfma_f32_16x16x32_f16(fa[m], fb[n], acc[m][n], 0, 0, 0);
    __builtin_amdgcn_s_barrier();
  }
  #pragma unroll
  for (int m = 0; m < MR; ++m)
    #pragma unroll
    for (int n = 0; n < 4; ++n)
      #pragma unroll
      for (int i = 0; i < 4; ++i) {
        const int r = m0 + wr * (BM / 2) + m * 16 + kseg * 4 + i;  // row=(lane>>4)*4+i (m89)
        const int c = n0 + wc * 64 + n * 16 + lrow;                // col=lane&15
        Cg[(long)r * ldc + c] = (CT)acc[m][n][i];
      }
}

// ---------------------------------------------------------------------------
// Output projection GEMM (R18): 64x128 tile, BK=64, 2-buffer, 4 waves.
// ---------------------------------------------------------------------------
__global__ __launch_bounds__(256) void gemm_out_kernel(
    const _Float16* __restrict__ Ag, const _Float16* __restrict__ Btg,
    float* __restrict__ Cg, int K, int lda, int ldb, int ldc, int mtiles)
{
  __shared__ _Float16 As[2][64 * 64];
  __shared__ _Float16 Bs[2][128 * 64];
  const int tid = threadIdx.x;
  const int lane = tid & 63, wid = tid >> 6;
  const int cpx = gridDim.x >> 3;
  const int wg = ((int)blockIdx.x & 7) * cpx + ((int)blockIdx.x >> 3);
  const int m0 = (wg % mtiles) * 64;
  const int n0 = (wg / mtiles) * 128;
  const _Float16* Ap = Ag + (long)m0 * lda;
  const _Float16* Bp = Btg + (long)n0 * ldb;
  const int wr = wid >> 1, wc = wid & 1;
  const int lrow = lane & 15, kseg = lane >> 4;

  auto stage = [&](int b, int k0) {
    #pragma unroll
    for (int i = 0; i < 2; ++i) {                 // A: 512 chunks (8/row)
      const int cbase = (i * 4 + wid) * 64;
      const int c = cbase + lane;
      const int row = c >> 3, slot = c & 7;
      gload16(Ap + (long)row * lda + k0 + (slot ^ (row & 7)) * 8,
              (char*)As[b] + cbase * 16);
    }
    #pragma unroll
    for (int i = 0; i < 4; ++i) {                 // B: 1024 chunks (8/row)
      const int cbase = (i * 4 + wid) * 64;
      const int c = cbase + lane;
      const int row = c >> 3, slot = c & 7;
      gload16(Bp + (long)row * ldb + k0 + (slot ^ (row & 7)) * 8,
              (char*)Bs[b] + cbase * 16);
    }
  };

  const int nt = K >> 6;                          // K-tiles of 64
  f32x4 acc[2][4] = {};
  stage(0, 0);
  int buf = 0;
  for (int t = 0; t < nt; ++t) {
    if (t + 1 < nt) {
      stage(buf ^ 1, (t + 1) * 64);               // prefetch next tile
      asm volatile("s_waitcnt vmcnt(6)" ::: "memory");  // t's 6 loads done
    } else {
      asm volatile("s_waitcnt vmcnt(0)" ::: "memory");
    }
    __builtin_amdgcn_s_barrier();
    __builtin_amdgcn_sched_barrier(0);
    #pragma unroll
    for (int kk = 0; kk < 2; ++kk) {              // two K=32 sub-steps
      f16x8 fa[2], fb[4];
      #pragma unroll
      for (int m = 0; m < 2; ++m) {
        const int row = wr * 32 + m * 16 + lrow;
        fa[m] = *(const f16x8*)&As[buf][row * 64 + (((kk * 4 + kseg) ^ (row & 7)) << 3)];
      }
      #pragma unroll
      for (int n = 0; n < 4; ++n) {
        const int row = wc * 64 + n * 16 + lrow;
        fb[n] = *(const f16x8*)&Bs[buf][row * 64 + (((kk * 4 + kseg) ^ (row & 7)) << 3)];
      }
      #pragma unroll
      for (int m = 0; m < 2; ++m)
        #pragma unroll
        for (int n = 0; n < 4; ++n)
          acc[m][n] = __builtin_amdgcn_mfma_f32_16x16x32_f16(fa[m], fb[n], acc[m][n], 0, 0, 0);
    }
    __builtin_amdgcn_s_barrier();
    buf ^= 1;
  }
  #pragma unroll
  for (int m = 0; m < 2; ++m)
    #pragma unroll
    for (int n = 0; n < 4; ++n)
      #pragma unroll
      for (int i = 0; i < 4; ++i) {
        const int r = m0 + wr * 32 + m * 16 + kseg * 4 + i;
        const int c = n0 + wc * 64 + n * 16 + lrow;
        Cg[(long)r * ldc + c] = acc[m][n][i];
      }
}

// ---------------------------------------------------------------------------
// Merged mid stage (one launch): gates (wave-scan, z from qkvo) + V^T.
// Gate arrays pre-scaled for exp2-based attention (R21).
// ---------------------------------------------------------------------------
__global__ __launch_bounds__(256) void mid_kernel(
    const _Float16* __restrict__ qkvo, _Float16* __restrict__ vt,
    const float* __restrict__ bi, const float* __restrict__ bfg,
    float* __restrict__ aArr, float* __restrict__ mArr, float* __restrict__ vMArr)
{
  __shared__ float shmem[64][65];
  const int tid = threadIdx.x;
  int t = blockIdx.x;
  if (t < NBH) {
    const int bh = t;
    const int b = bh >> 3, h = bh & 7;
    const int lane = tid & 63, wid = tid >> 6;
    float* wsum = &shmem[0][0];
    float* wmax = &shmem[1][0];
    const float bih = bi[h], bfh = bfg[h];
    const int s4 = tid * 4;
    const _Float16* zb = qkvo + (long)(b * S_LEN + s4) * NQKVO;
    float zf[4], zi[4];
    #pragma unroll
    for (int k = 0; k < 4; ++k) {
      zi[k] = 15.0f * tanhf(((float)zb[(long)k * NQKVO + 4608 + h] + bih) * (1.0f / 15.0f));
      zf[k] = 15.0f * tanhf(((float)zb[(long)k * NQKVO + 4616 + h] + bfh) * (1.0f / 15.0f));
    }
    float lg[4];
    #pragma unroll
    for (int k = 0; k < 4; ++k)
      lg[k] = fminf(zf[k], 0.0f) - log1pf(expf(-fabsf(zf[k])));
    float c0 = lg[0], c1 = c0 + lg[1], c2 = c1 + lg[2], c3 = c2 + lg[3];
    float ts = c3;
    #pragma unroll
    for (int off = 1; off < 64; off <<= 1) {
      const float o = __shfl_up(ts, off);
      if (lane >= off) ts += o;
    }
    const float texcl = ts - c3;
    if (lane == 63) wsum[wid] = ts;
    __syncthreads();
    float woff = 0.0f;
    for (int w = 0; w < wid; ++w) woff += wsum[w];
    const float base = woff + texcl;
    const float cf[4] = { base + c0, base + c1, base + c2, base + c3 };
    const float a[4] = { zi[0] - cf[0], zi[1] - cf[1], zi[2] - cf[2], zi[3] - cf[3] };
    float l1 = fmaxf(a[0], a[1]), l3 = fmaxf(fmaxf(l1, a[2]), a[3]);
    float incl = l3;
    #pragma unroll
    for (int off = 1; off < 64; off <<= 1) {
      const float o = __shfl_up(incl, off);
      if (lane >= off) incl = fmaxf(incl, o);
    }
    float excl = __shfl_up(incl, 1);
    if (lane == 0) excl = -3.0e38f;
    if (lane == 63) wmax[wid] = incl;
    __syncthreads();
    float wpre = -3.0e38f;
    for (int w = 0; w < wid; ++w) wpre = fmaxf(wpre, wmax[w]);
    const float pre = fmaxf(wpre, excl);
    float mm[4];
    mm[0] = fmaxf(pre, a[0]); mm[1] = fmaxf(mm[0], a[1]);
    mm[2] = fmaxf(mm[1], a[2]); mm[3] = fmaxf(mm[2], a[3]);
    float4 av = { (a[0] - LN16) * LOG2E, (a[1] - LN16) * LOG2E,
                  (a[2] - LN16) * LOG2E, (a[3] - LN16) * LOG2E };
    float4 mv = { mm[0] * LOG2E, mm[1] * LOG2E, mm[2] * LOG2E, mm[3] * LOG2E };
    float4 vv = { (cf[0] + mm[0]) * LOG2E, (cf[1] + mm[1]) * LOG2E,
                  (cf[2] + mm[2]) * LOG2E, (cf[3] + mm[3]) * LOG2E };
    *(float4*)(aArr + (long)bh * S_LEN + s4) = av;
    *(float4*)(mArr + (long)bh * S_LEN + s4) = mv;
    *(float4*)(vMArr + (long)bh * S_LEN + s4) = vv;
  } else {
    t -= NBH;
    const int z = t >> 6, rem = t & 63;
    const long c0 = (long)(rem & 3) * 64;    // d-tile
    const long r0 = (long)(rem >> 2) * 64;   // s-tile
    const _Float16* ipt = qkvo + (long)z * S_LEN * NQKVO + 2304;
    _Float16* op = vt + (long)z * DH_ * S_LEN;
    const int lx = tid & 63, ly = tid >> 6;
    #pragma unroll
    for (int i = 0; i < 16; ++i)
      shmem[ly + i * 4][lx] = (float)ipt[(r0 + ly + i * 4) * NQKVO + c0 + lx];
    __syncthreads();
    #pragma unroll
    for (int i = 0; i < 16; ++i)
      op[(c0 + ly + i * 4) * S_LEN + r0 + lx] = f2h(shmem[lx][ly + i * 4]);
  }
}

// ---------------------------------------------------------------------------
// Fused mLSTM attention + LN + output gate, triangle-paired, QBLK=32,
// 512 threads / 8 waves.  R22: cross-pass K-frag prefetch — next pass's
// first K load issues during the weighting phase, hiding its L2 latency
// under V-loads + PV MFMAs (T14 issue-early across the phase boundary).
// ---------------------------------------------------------------------------
__global__ __launch_bounds__(512) void att_fused_kernel(
    const _Float16* __restrict__ qkvo, const _Float16* __restrict__ vt,
    const float* __restrict__ aArr, const float* __restrict__ mArr,
    const float* __restrict__ vMArr, const float* __restrict__ gamma,
    _Float16* __restrict__ ub)
{
  __shared__ _Float16 Qs[2][32 * 256];   // swizzled: 32 chunks/row, ^(row&7)
  __shared__ _Float16 Ws[2][32 * 128];   // swizzled: 16 chunks/row, ^((row&7)<<1)
  __shared__ float nsh[2][8][32];
  __shared__ float s2sh[2][8][32];
  __shared__ float invs[2][32];
  __shared__ float musl[2][32], rssl[2][32];
  const int tid = threadIdx.x;
  const int lane = tid & 63, wid = tid >> 6;     // 8 waves
  const int bh = blockIdx.y;
  const int b = bh >> 3, h = bh & 7;
  const int r0[2] = { (int)blockIdx.x * 32, (31 - (int)blockIdx.x) * 32 };
  const _Float16* Qg = qkvo + (long)(b * S_LEN) * NQKVO + h * DH_;
  const _Float16* Kg = qkvo + (long)(b * S_LEN) * NQKVO + 2048;
  const _Float16* Og = qkvo + (long)(b * S_LEN) * NQKVO + 2560 + h * DH_;
  const _Float16* Vt = vt + (long)b * DH_ * S_LEN;
  const float* aA = aArr + (long)bh * S_LEN;
  const float* mA = mArr + (long)bh * S_LEN;
  const float* gam = gamma + h * DH_;
  const int lrow = lane & 15, kseg = lane >> 4;
  const int tbase = 16 * wid;                    // QK t-slice per wave
  const int dbase = 32 * wid;                    // PV d-slice per wave

  #pragma unroll
  for (int i = 0; i < 4; ++i) {
    const int cbase = (i * 8 + wid) * 64;        // wave-uniform
    const int c = cbase + lane;
    const int sub = c >> 10, row = (c >> 5) & 31, slot = c & 31;
    gload16(Qg + (long)(r0[sub] + row) * NQKVO + (slot ^ (row & 7)) * 8,
            (char*)Qs + cbase * 16);
  }

  float m_s[2][2][4];
  #pragma unroll
  for (int sub = 0; sub < 2; ++sub)
    #pragma unroll
    for (int m = 0; m < 2; ++m)
      #pragma unroll
      for (int i = 0; i < 4; ++i)
        m_s[sub][m][i] = mA[r0[sub] + m * 16 + kseg * 4 + i];
  __syncthreads();   // Q staged (drains vmcnt)

  f32x4 hacc[2][2][2] = {};
  float nacc[2][2][4] = {};
  // R22: first K-frag of pass 0 issued before the pass loop
  f16x8 fb0 = *(const f16x8*)(Kg + (long)(tbase + lrow) * NQKVO + kseg * 8);
  for (int n0 = 0; n0 <= r0[1]; n0 += 128) {
    f32x4 acc[2][2] = {};
    f16x8 fb = fb0, fbn;
    #pragma unroll
    for (int k0 = 0; k0 < DH_; k0 += 32) {
      if (k0 + 32 < DH_)
        fbn = *(const f16x8*)(Kg + (long)(n0 + tbase + lrow) * NQKVO + k0 + 32 + kseg * 8);
      const int chunk = (k0 >> 3) + kseg;
      __builtin_amdgcn_s_setprio(1);
      #pragma unroll
      for (int sub = 0; sub < 2; ++sub) {
        if (n0 > r0[sub]) continue;
        #pragma unroll
        for (int m = 0; m < 2; ++m) {
          const int qrow = m * 16 + lrow;
          const f16x8 fa = *(const f16x8*)&Qs[sub][qrow * 256 + ((chunk ^ (qrow & 7)) << 3)];
          acc[sub][m] = __builtin_amdgcn_mfma_f32_16x16x32_f16(fa, fb, acc[sub][m], 0, 0, 0);
        }
      }
      __builtin_amdgcn_s_setprio(0);
      fb = fbn;
    }
    // ---- R22: issue next pass's first K-frag now (latency hides under
    //      weighting + V-loads + PV).  Wave-uniform guard avoids OOB. ----
    if (n0 + 128 <= r0[1])
      fb0 = *(const f16x8*)(Kg + (long)(n0 + 128 + tbase + lrow) * NQKVO + kseg * 8);
    // ---- weighting -> Ws (swizzled), exp2 + fast full-tile path ----
    const float a_t = aA[n0 + tbase + lrow];
    const int t = tbase + lrow;                   // local col 0..127 (const/thread)
    #pragma unroll
    for (int sub = 0; sub < 2; ++sub) {
      if (n0 > r0[sub]) continue;
      if (n0 + 127 <= r0[sub]) {                  // full tile: no causal check
        #pragma unroll
        for (int m = 0; m < 2; ++m)
          #pragma unroll
          for (int i = 0; i < 4; ++i) {
            const int sr = m * 16 + kseg * 4 + i;
            const float w = acc[sub][m][i] * exp2f(a_t - m_s[sub][m][i]);
            nacc[sub][m][i] += w;
            Ws[sub][sr * 128 + (((t >> 3) ^ ((sr & 7) << 1)) << 3) + (t & 7)] = f2h(w);
          }
      } else {
        #pragma unroll
        for (int m = 0; m < 2; ++m)
          #pragma unroll
          for (int i = 0; i < 4; ++i) {
            const int sr = m * 16 + kseg * 4 + i;
            float w = 0.0f;
            if (n0 + t <= r0[sub] + sr)
              w = acc[sub][m][i] * exp2f(a_t - m_s[sub][m][i]);
            nacc[sub][m][i] += w;
            Ws[sub][sr * 128 + (((t >> 3) ^ ((sr & 7) << 1)) << 3) + (t & 7)] = f2h(w);
          }
      }
    }
    f16x8 vb[2], vbn[2];
    #pragma unroll
    for (int n = 0; n < 2; ++n)
      vb[n] = *(const f16x8*)(Vt + (long)(dbase + n * 16 + lrow) * S_LEN + n0 + kseg * 8);
    __syncthreads();
    #pragma unroll
    for (int kt = 0; kt < 128; kt += 32) {
      if (kt + 32 < 128) {
        #pragma unroll
        for (int n = 0; n < 2; ++n)
          vbn[n] = *(const f16x8*)(Vt + (long)(dbase + n * 16 + lrow) * S_LEN + n0 + kt + 32 + kseg * 8);
      }
      const int chunk = (kt >> 3) + kseg;
      __builtin_amdgcn_s_setprio(1);
      #pragma unroll
      for (int sub = 0; sub < 2; ++sub) {
        if (n0 > r0[sub]) continue;
        #pragma unroll
        for (int m = 0; m < 2; ++m) {
          const int row = m * 16 + lrow;
          const f16x8 wa = *(const f16x8*)&Ws[sub][row * 128 + ((chunk ^ ((row & 7) << 1)) << 3)];
          #pragma unroll
          for (int n = 0; n < 2; ++n)
            hacc[sub][m][n] = __builtin_amdgcn_mfma_f32_16x16x32_f16(wa, vb[n], hacc[sub][m][n], 0, 0, 0);
        }
      }
      __builtin_amdgcn_s_setprio(0);
      vb[0] = vbn[0]; vb[1] = vbn[1];
    }
    __syncthreads();   // Ws reads done before next pass overwrites
  }
  #pragma unroll
  for (int sub = 0; sub < 2; ++sub)
    #pragma unroll
    for (int m = 0; m < 2; ++m)
      #pragma unroll
      for (int i = 0; i < 4; ++i) {
        float v = nacc[sub][m][i];
        v += __shfl_xor(v, 1); v += __shfl_xor(v, 2);
        v += __shfl_xor(v, 4); v += __shfl_xor(v, 8);
        if (lrow == 0) nsh[sub][wid][m * 16 + kseg * 4 + i] = v;
      }
  __syncthreads();
  if (tid < 64) {
    const int sub = tid >> 5, sr = tid & 31;
    float tot = 0.0f;
    #pragma unroll
    for (int w = 0; w < 8; ++w) tot += nsh[sub][w][sr];
    const float vm = vMArr[(long)bh * S_LEN + r0[sub] + sr];   // pre-scaled by log2e
    const float vecN = fmaxf(fabsf(tot), exp2f(-vm));
    invs[sub][sr] = 1.0f / (vecN + 1e-6f);
  }
  __syncthreads();
  #pragma unroll
  for (int sub = 0; sub < 2; ++sub)
    #pragma unroll
    for (int m = 0; m < 2; ++m)
      #pragma unroll
      for (int i = 0; i < 4; ++i) {
        const int row = m * 16 + kseg * 4 + i;
        const float inv = invs[sub][row];
        hacc[sub][m][0][i] *= inv;
        hacc[sub][m][1][i] *= inv;
        float s1 = hacc[sub][m][0][i] + hacc[sub][m][1][i];
        float s2 = hacc[sub][m][0][i] * hacc[sub][m][0][i]
                 + hacc[sub][m][1][i] * hacc[sub][m][1][i];
        s1 += __shfl_xor(s1, 1); s2 += __shfl_xor(s2, 1);
        s1 += __shfl_xor(s1, 2); s2 += __shfl_xor(s2, 2);
        s1 += __shfl_xor(s1, 4); s2 += __shfl_xor(s2, 4);
        s1 += __shfl_xor(s1, 8); s2 += __shfl_xor(s2, 8);
        if (lrow == 0) { nsh[sub][wid][row] = s1; s2sh[sub][wid][row] = s2; }
      }
  __syncthreads();
  if (tid < 64) {
    const int sub = tid >> 5, sr = tid & 31;
    float s1 = 0.0f, s2 = 0.0f;
    #pragma unroll
    for (int w = 0; w < 8; ++w) { s1 += nsh[sub][w][sr]; s2 += s2sh[sub][w][sr]; }
    const float mu = s1 * (1.0f / 256.0f);
    const float var = s2 * (1.0f / 256.0f) - mu * mu;
    musl[sub][sr] = mu;
    rssl[sub][sr] = rsqrtf(var + 1e-6f);
  }
  __syncthreads();
  #pragma unroll
  for (int sub = 0; sub < 2; ++sub)
    #pragma unroll
    for (int m = 0; m < 2; ++m)
      #pragma unroll
      for (int n = 0; n < 2; ++n)
        #pragma unroll
        for (int i = 0; i < 4; ++i) {
          const int row = m * 16 + kseg * 4 + i;
          const int d = dbase + n * 16 + lrow;
          const long gr = r0[sub] + row;
          const float hn = (hacc[sub][m][n][i] - musl[sub][row]) * rssl[sub][row] * gam[d];
          const float o = (float)Og[((long)gr) * NQKVO + d];
          ub[(long)(b * S_LEN + gr) * EMB + h * DH_ + d] =
              f2h(hn * (1.0f / (1.0f + expf(-o))));
        }
}

// ---------------------------------------------------------------------------
extern "C" void kernel_launch(void* const* d_in, const int* in_sizes, int n_in,
                              void* d_out, int out_size, void* d_ws, size_t ws_size,
                              hipStream_t stream)
{
  (void)in_sizes; (void)n_in; (void)out_size; (void)ws_size;
  const float* x     = (const float*)d_in[0];
  const float* Wq    = (const float*)d_in[1];
  const float* Wk    = (const float*)d_in[2];
  const float* Wv    = (const float*)d_in[3];
  const float* Wog   = (const float*)d_in[4];
  const float* Wi    = (const float*)d_in[5];
  const float* bi    = (const float*)d_in[6];
  const float* Wf    = (const float*)d_in[7];
  const float* bfg   = (const float*)d_in[8];
  const float* gamma = (const float*)d_in[9];
  const float* Wout  = (const float*)d_in[10];

  char* base = (char*)d_ws;
  size_t off = 0;
  auto take = [&](size_t bytes) -> char* {
    char* p = base + off;
    off += (bytes + 255) & ~(size_t)255;
    return p;
  };
  _Float16* xh    = (_Float16*)take((size_t)TOKENS * EMB * 2);        //  8 MB
  _Float16* WcatT = (_Float16*)take((size_t)NQKVO * EMB * 2);         // 19.4 MB
  _Float16* WoutT = (_Float16*)take((size_t)EMB * EMB * 2);           //  8 MB
  _Float16* qkvo  = (_Float16*)take((size_t)TOKENS * NQKVO * 2);      // 19.4 MB
  _Float16* vt    = (_Float16*)take((size_t)2 * DH_ * S_LEN * 2);     //  1 MB
  _Float16* ub    = (_Float16*)take((size_t)TOKENS * EMB * 2);        //  8 MB
  float*    aA    = (float*)take((size_t)NBH * S_LEN * 4);
  float*    mA    = (float*)take((size_t)NBH * S_LEN * 4);
  float*    vM    = (float*)take((size_t)NBH * S_LEN * 4);
  float*    y     = (float*)d_out;

  const dim3 blk(256);
  // --- merged prep: x cast + all weight transposes + i/f rows (1 launch) ---
  prep_kernel<<<dim3(TOKENS + 3328 + 64), blk, 0, stream>>>(
      x, Wq, Wk, Wv, Wog, Wout, Wi, Wf, xh, WcatT, WoutT);
  // --- fused QKVO+if projection: [2048,4736] = xh @ WcatT^T (16m x 37n) ---
  gemm_bt_kernel<_Float16, 128><<<dim3(16 * 37), blk, 0, stream>>>(
      xh, WcatT, qkvo, EMB, EMB, EMB, NQKVO, 16);
  // --- merged mid: gates (from qkvo z-cols, pre-scaled for exp2) + V^T ---
  mid_kernel<<<dim3(NBH + 128), blk, 0, stream>>>(qkvo, vt, bi, bfg, aA, mA, vM);
  // --- fused mLSTM backend + LN + output gate (writes ub directly) ---
  att_fused_kernel<<<dim3(16, NBH), dim3(512), 0, stream>>>(
      qkvo, vt, aA, mA, vM, gamma, ub);
  // --- output projection: BM=64/BK=64 2-buf, 512 blocks (R18) ---
  gemm_out_kernel<<<dim3(32 * 16), blk, 0, stream>>>(
      ub, WoutT, y, EMB, EMB, EMB, EMB, 32);
}